// Round 5
// baseline (571.419 us; speedup 1.0000x reference)
//
#include <hip/hip_runtime.h>

#define N_BUS 200000
#define N_GEN 50000
#define E_BB 1600000
#define E_GB 400000
#define E_BG 400000
#define H 32
#define NBINS 1024   // max coarse buckets (>= ceil(200000/256) = 782)
#define EPT 16       // edges per thread in partition (chunk = 4096)

// ---------------------------------------------------------------------------
// Coarse histogram over 256-dst buckets, LDS-privatized.
__global__ __launch_bounds__(256) void coarse_hist_kernel(const int* __restrict__ dst,
                                                          int nE, unsigned* __restrict__ bcnt) {
    __shared__ unsigned h[NBINS];
    for (int i = threadIdx.x; i < NBINS; i += 256) h[i] = 0;
    __syncthreads();
    for (int e = blockIdx.x * 256 + threadIdx.x; e < nE; e += gridDim.x * 256)
        atomicAdd(&h[(unsigned)dst[e] >> 8], 1u);
    __syncthreads();
    for (int i = threadIdx.x; i < NBINS; i += 256)
        if (h[i]) atomicAdd(&bcnt[i], h[i]);
}

// In-place exclusive scan of exactly 1024 entries, single block (256 thr x 4).
__global__ __launch_bounds__(256) void scan1024_kernel(unsigned* __restrict__ a) {
    __shared__ unsigned sh[256];
    int tid = threadIdx.x;
    int base = tid * 4;
    unsigned v[4], ts = 0;
#pragma unroll
    for (int q = 0; q < 4; q++) { v[q] = a[base + q]; ts += v[q]; }
    sh[tid] = ts;
    __syncthreads();
#pragma unroll
    for (int d = 1; d < 256; d <<= 1) {
        unsigned t = (tid >= d) ? sh[tid - d] : 0u;
        __syncthreads();
        sh[tid] += t;
        __syncthreads();
    }
    unsigned run = sh[tid] - ts;
#pragma unroll
    for (int q = 0; q < 4; q++) { a[base + q] = run; run += v[q]; }
}

// Partition scatter: each block stages a 4096-edge chunk, reserves per-bucket
// runs with ONE global atomic per (block,bucket), writes packed (dstl<<24|src)
// into block-private runs (same-block line ownership -> low write amp).
__global__ __launch_bounds__(256) void partition_kernel(const int* __restrict__ src,
                                                        const int* __restrict__ dst, int nE,
                                                        unsigned* __restrict__ cursor,
                                                        unsigned* __restrict__ pairs) {
    __shared__ unsigned hist[NBINS];
    __shared__ unsigned base[NBINS];
    const int tid = threadIdx.x;
    const int cbase = blockIdx.x * (256 * EPT);

    unsigned es[EPT], ed[EPT];
#pragma unroll
    for (int q = 0; q < EPT; q++) {
        int i = cbase + q * 256 + tid;
        if (i < nE) { es[q] = (unsigned)src[i]; ed[q] = (unsigned)dst[i]; }
        else ed[q] = 0xFFFFFFFFu;
    }
    for (int i = tid; i < NBINS; i += 256) hist[i] = 0;
    __syncthreads();
#pragma unroll
    for (int q = 0; q < EPT; q++)
        if (ed[q] != 0xFFFFFFFFu) atomicAdd(&hist[ed[q] >> 8], 1u);
    __syncthreads();
    for (int i = tid; i < NBINS; i += 256) {
        unsigned c = hist[i];
        base[i] = c ? atomicAdd(&cursor[i], c) : 0u;
        hist[i] = 0;  // reuse as local cursor
    }
    __syncthreads();
#pragma unroll
    for (int q = 0; q < EPT; q++) {
        if (ed[q] != 0xFFFFFFFFu) {
            unsigned b = ed[q] >> 8;
            unsigned off = atomicAdd(&hist[b], 1u);
            pairs[base[b] + off] = ((ed[q] & 255u) << 24) | es[q];
        }
    }
}

// Fine CSR: one block per coarse bucket. Builds per-dst row ends (rs) and
// dst-sorted src lists (esrc) within the bucket's contiguous region.
__global__ __launch_bounds__(256) void fine_csr_kernel(const unsigned* __restrict__ cursor,
                                                       const unsigned* __restrict__ pairs,
                                                       unsigned* __restrict__ rs,
                                                       unsigned* __restrict__ esrc, int nDst) {
    __shared__ unsigned cnt[256];
    __shared__ unsigned sh[256];
    const int tid = threadIdx.x;
    const int b = blockIdx.x;
    const unsigned start = b ? cursor[b - 1] : 0u;
    const unsigned end = cursor[b];

    cnt[tid] = 0;
    __syncthreads();
    for (unsigned k = start + tid; k < end; k += 256)
        atomicAdd(&cnt[pairs[k] >> 24], 1u);
    __syncthreads();
    unsigned c = cnt[tid];
    sh[tid] = c;
    __syncthreads();
#pragma unroll
    for (int d = 1; d < 256; d <<= 1) {
        unsigned t = (tid >= d) ? sh[tid - d] : 0u;
        __syncthreads();
        sh[tid] += t;
        __syncthreads();
    }
    int gd = b * 256 + tid;
    if (gd < nDst) rs[gd] = start + sh[tid];  // inclusive row end
    cnt[tid] = sh[tid] - c;                   // exclusive offset -> cursor
    __syncthreads();
    for (unsigned k = start + tid; k < end; k += 256) {
        unsigned p = pairs[k];
        unsigned off = atomicAdd(&cnt[p >> 24], 1u);
        esrc[start + off] = p & 0x00FFFFFFu;
    }
}

// ---------------------------------------------------------------------------
// Prep: concatenate weights into k-major Wcat[K][NOUT] per transform, fold
// Wr sums and biases. Bus (NOUT=96): [Wl_bb | Wl_bg | Wr_bb+Wr_gb];
// gen (NOUT=64): [Wl_gb | Wr_bg]. Bias vectors aligned to cols (0 for y cols).
__global__ __launch_bounds__(256) void prep_kernel(
    const float* __restrict__ l1_bb_Wl, const float* __restrict__ l1_bb_bl, const float* __restrict__ l1_bb_Wr,
    const float* __restrict__ l1_gb_Wl, const float* __restrict__ l1_gb_bl, const float* __restrict__ l1_gb_Wr,
    const float* __restrict__ l1_bg_Wl, const float* __restrict__ l1_bg_bl, const float* __restrict__ l1_bg_Wr,
    const float* __restrict__ l2_bb_Wl, const float* __restrict__ l2_bb_bl, const float* __restrict__ l2_bb_Wr,
    const float* __restrict__ l2_gb_Wl, const float* __restrict__ l2_gb_bl, const float* __restrict__ l2_gb_Wr,
    const float* __restrict__ l2_bg_Wl, const float* __restrict__ l2_bg_bl, const float* __restrict__ l2_bg_Wr,
    float* __restrict__ W1b, float* __restrict__ B1b,
    float* __restrict__ W1g, float* __restrict__ B1g,
    float* __restrict__ W2b, float* __restrict__ B2b,
    float* __restrict__ W2g, float* __restrict__ B2g)
{
    int t = blockIdx.x * 256 + threadIdx.x;
    int NT = gridDim.x * 256;
    for (int idx = t; idx < 64 * 32; idx += NT) {
        int k = idx >> 5, j = idx & 31;
        W1b[k * 96 + j]      = l1_bb_Wl[idx];
        W1b[k * 96 + 32 + j] = l1_bg_Wl[idx];
        W1b[k * 96 + 64 + j] = l1_bb_Wr[idx] + l1_gb_Wr[idx];
        W1g[k * 64 + j]      = l1_gb_Wl[idx];
        W1g[k * 64 + 32 + j] = l1_bg_Wr[idx];
    }
    for (int idx = t; idx < 32 * 32; idx += NT) {
        int k = idx >> 5, j = idx & 31;
        W2b[k * 96 + j]      = l2_bb_Wl[idx];
        W2b[k * 96 + 32 + j] = l2_bg_Wl[idx];
        W2b[k * 96 + 64 + j] = l2_bb_Wr[idx] + l2_gb_Wr[idx];
        W2g[k * 64 + j]      = l2_gb_Wl[idx];
        W2g[k * 64 + 32 + j] = l2_bg_Wr[idx];
    }
    if (t < 96) {
        B1b[t] = (t < 64) ? 0.0f : l1_bb_bl[t - 64] + l1_gb_bl[t - 64];
        B2b[t] = (t < 64) ? 0.0f : l2_bb_bl[t - 64] + l2_gb_bl[t - 64];
    }
    if (t < 64) {
        B1g[t] = (t < 32) ? 0.0f : l1_bg_bl[t - 32];
        B2g[t] = (t < 32) ? 0.0f : l2_bg_bl[t - 32];
    }
}

// ---------------------------------------------------------------------------
// Node transform v3: LDS-tiled for full-line global traffic both directions.
//  1) stage 256-row x tile: coalesced float4 global reads -> LDS (stride K+1,
//     2 lanes/bank = free).
//  2) compute: thread = node, k-loop ds_read_b32 + NOUT FMAs, acc in VGPRs.
//  3) epilogue: acc chunk -> LDS (stride 33) -> coalesced float4 stores.
// x may alias o2 (in-place root write): block owns its 256 rows, all reads
// complete (tile staged + syncthreads) before any store. MINW sizes VGPR cap.
template <int K, int NOUT, bool RELU_IN, int MINW>
__global__ __launch_bounds__(256, MINW) void transform3_kernel(
    const float* x, int n,
    const float* __restrict__ Wcat, const float* __restrict__ bias,
    float* __restrict__ o0, float* __restrict__ o1, float* o2)
{
    constexpr int XS = K + 1;     // x-tile row stride (floats)
    constexpr int OS = 33;        // out-chunk row stride
    __shared__ float lds[256 * XS];   // >= 256*OS since K >= 32

    const int tid = threadIdx.x;
    const int base = blockIdx.x * 256;
    const int rows = min(256, n - base);

    // ---- stage x tile ----
    {
        const float4* xg = (const float4*)(x + (size_t)base * K);
        const int total4 = rows * (K / 4);
        for (int q = tid; q < total4; q += 256) {
            float4 v = xg[q];
            int idx = q * 4;
            int r = idx / K, c = idx % K;
            float* p = &lds[r * XS + c];
            p[0] = v.x; p[1] = v.y; p[2] = v.z; p[3] = v.w;
        }
    }
    __syncthreads();

    // ---- compute ----
    float acc[NOUT];
#pragma unroll
    for (int j = 0; j < NOUT; j++) acc[j] = bias[j];

    if (tid < rows) {
        const float* xr = &lds[tid * XS];
        for (int k = 0; k < K; ++k) {
            float xk = xr[k];
            if (RELU_IN) xk = fmaxf(xk, 0.0f);
            const float* __restrict__ wr = Wcat + k * NOUT;
#pragma unroll
            for (int j = 0; j < NOUT; j++) acc[j] = fmaf(xk, wr[j], acc[j]);
        }
    }

    // ---- epilogue: per-chunk LDS transpose -> coalesced stores ----
    constexpr int NCH = NOUT / 32;
    float* const outs[3] = {o0, (NOUT == 96) ? o1 : o2, o2};
#pragma unroll
    for (int c = 0; c < NCH; c++) {
        __syncthreads();
        if (tid < rows) {
#pragma unroll
            for (int k = 0; k < 32; k++) lds[tid * OS + k] = acc[c * 32 + k];
        }
        __syncthreads();
        float4* og = (float4*)(outs[c] + (size_t)base * 32);
        const int total4 = rows * 8;
        for (int q = tid; q < total4; q += 256) {
            int idx = q * 4;
            int r = idx >> 5, cc = idx & 31;
            const float* p = &lds[r * OS + cc];
            og[q] = make_float4(p[0], p[1], p[2], p[3]);
        }
    }
}

// ---------------------------------------------------------------------------
// Pull aggregation: h[node] += mean_A(yA[srcs]) (+ mean_B(yB[srcs])).
// 8 threads per node, float4 per thread. rs row i spans [rs[i-1], rs[i]).
template <bool HASB>
__global__ __launch_bounds__(256) void pull_kernel(
    const unsigned* __restrict__ rsA, const unsigned* __restrict__ eA, const float* __restrict__ yA,
    const unsigned* __restrict__ rsB, const unsigned* __restrict__ eB, const float* __restrict__ yB,
    float* __restrict__ h, int n)
{
    unsigned t = blockIdx.x * 256u + threadIdx.x;
    unsigned node = t >> 3;
    int j = (int)(t & 7u) * 4;
    if (node >= (unsigned)n) return;

    float4 r = *(const float4*)(h + (size_t)node * H + j);  // root term

    {
        unsigned k0 = node ? rsA[node - 1] : 0u;
        unsigned k1 = rsA[node];
        float4 acc = make_float4(0.f, 0.f, 0.f, 0.f);
        for (unsigned k = k0; k < k1; ++k) {
            unsigned s = eA[k];
            const float4 v = *(const float4*)(yA + (size_t)s * H + j);
            acc.x += v.x; acc.y += v.y; acc.z += v.z; acc.w += v.w;
        }
        unsigned c = k1 - k0;
        float inv = 1.0f / (float)(c > 1u ? c : 1u);
        r.x += acc.x * inv; r.y += acc.y * inv; r.z += acc.z * inv; r.w += acc.w * inv;
    }
    if (HASB) {
        unsigned k0 = node ? rsB[node - 1] : 0u;
        unsigned k1 = rsB[node];
        float4 acc = make_float4(0.f, 0.f, 0.f, 0.f);
        for (unsigned k = k0; k < k1; ++k) {
            unsigned s = eB[k];
            const float4 v = *(const float4*)(yB + (size_t)s * H + j);
            acc.x += v.x; acc.y += v.y; acc.z += v.z; acc.w += v.w;
        }
        unsigned c = k1 - k0;
        float inv = 1.0f / (float)(c > 1u ? c : 1u);
        r.x += acc.x * inv; r.y += acc.y * inv; r.z += acc.z * inv; r.w += acc.w * inv;
    }

    *(float4*)(h + (size_t)node * H + j) = r;
}

// ---------------------------------------------------------------------------
// Head: out = relu(h) @ (lin0_W @ linf_W) + (lin0_b @ linf_W + linf_b).
template <int DOUT>
__global__ __launch_bounds__(256) void final_kernel(
    const float* __restrict__ h, int n,
    const float* __restrict__ lin0W, const float* __restrict__ lin0b,
    const float* __restrict__ linfW, const float* __restrict__ linfb,
    float* __restrict__ out)
{
    __shared__ float we[H * DOUT];
    __shared__ float be[DOUT];
    if (threadIdx.x < H * DOUT) {
        int k = threadIdx.x / DOUT, c = threadIdx.x % DOUT;
        float s = 0.0f;
        for (int m = 0; m < H; m++) s += lin0W[k * H + m] * linfW[m * DOUT + c];
        we[threadIdx.x] = s;
    }
    if (threadIdx.x >= 128 && threadIdx.x < 128 + DOUT) {
        int c = threadIdx.x - 128;
        float s = linfb[c];
        for (int m = 0; m < H; m++) s += lin0b[m] * linfW[m * DOUT + c];
        be[c] = s;
    }
    __syncthreads();

    int i = blockIdx.x * 256 + threadIdx.x;
    if (i >= n) return;

    const float4* hp = (const float4*)(h + (size_t)i * H);
    float acc[DOUT];
#pragma unroll
    for (int c = 0; c < DOUT; c++) acc[c] = be[c];
#pragma unroll
    for (int q = 0; q < H / 4; q++) {
        float4 v = hp[q];
        float vs[4] = {fmaxf(v.x, 0.0f), fmaxf(v.y, 0.0f), fmaxf(v.z, 0.0f), fmaxf(v.w, 0.0f)};
#pragma unroll
        for (int r = 0; r < 4; r++) {
            int k = q * 4 + r;
#pragma unroll
            for (int c = 0; c < DOUT; c++) acc[c] = fmaf(vs[r], we[k * DOUT + c], acc[c]);
        }
    }
    if constexpr (DOUT == 4) {
        *(float4*)(out + (size_t)i * 4) = make_float4(acc[0], acc[1], acc[2], acc[3]);
    } else {
        *(float2*)(out + (size_t)i * 2) = make_float2(acc[0], acc[1]);
    }
}

// ---------------------------------------------------------------------------
extern "C" void kernel_launch(void* const* d_in, const int* in_sizes, int n_in,
                              void* d_out, int out_size, void* d_ws, size_t ws_size,
                              hipStream_t stream) {
    const float* x_bus = (const float*)d_in[0];
    const float* x_gen = (const float*)d_in[1];
    const int* src_bb = (const int*)d_in[2];
    const int* dst_bb = (const int*)d_in[3];
    const int* src_gb = (const int*)d_in[4];
    const int* dst_gb = (const int*)d_in[5];
    const int* src_bg = (const int*)d_in[6];
    const int* dst_bg = (const int*)d_in[7];
    const float* l1_bb_Wl = (const float*)d_in[8];
    const float* l1_bb_bl = (const float*)d_in[9];
    const float* l1_bb_Wr = (const float*)d_in[10];
    const float* l1_gb_Wl = (const float*)d_in[11];
    const float* l1_gb_bl = (const float*)d_in[12];
    const float* l1_gb_Wr = (const float*)d_in[13];
    const float* l1_bg_Wl = (const float*)d_in[14];
    const float* l1_bg_bl = (const float*)d_in[15];
    const float* l1_bg_Wr = (const float*)d_in[16];
    const float* l2_bb_Wl = (const float*)d_in[17];
    const float* l2_bb_bl = (const float*)d_in[18];
    const float* l2_bb_Wr = (const float*)d_in[19];
    const float* l2_gb_Wl = (const float*)d_in[20];
    const float* l2_gb_bl = (const float*)d_in[21];
    const float* l2_gb_Wr = (const float*)d_in[22];
    const float* l2_bg_Wl = (const float*)d_in[23];
    const float* l2_bg_bl = (const float*)d_in[24];
    const float* l2_bg_Wr = (const float*)d_in[25];
    const float* lin0_bus_W = (const float*)d_in[26];
    const float* lin0_bus_b = (const float*)d_in[27];
    const float* linf_bus_W = (const float*)d_in[28];
    const float* linf_bus_b = (const float*)d_in[29];
    const float* lin0_gen_W = (const float*)d_in[30];
    const float* lin0_gen_b = (const float*)d_in[31];
    const float* linf_gen_W = (const float*)d_in[32];
    const float* linf_gen_b = (const float*)d_in[33];

    // Workspace layout (~101 MB).
    char* ws = (char*)d_ws;
    size_t off = 0;
    auto alloc = [&](size_t bytes) {
        char* p = ws + off;
        off += (bytes + 255) & ~(size_t)255;
        return p;
    };
    unsigned* rs_bb = (unsigned*)alloc((size_t)N_BUS * 4);
    unsigned* rs_gb = (unsigned*)alloc((size_t)N_BUS * 4);
    unsigned* rs_bg = (unsigned*)alloc((size_t)N_GEN * 4);
    unsigned* cur_bb = (unsigned*)alloc(NBINS * 4);
    unsigned* cur_gb = (unsigned*)alloc(NBINS * 4);
    unsigned* cur_bg = (unsigned*)alloc(NBINS * 4);
    unsigned* e_bb = (unsigned*)alloc((size_t)E_BB * 4);
    unsigned* e_gb = (unsigned*)alloc((size_t)E_GB * 4);
    unsigned* e_bg = (unsigned*)alloc((size_t)E_BG * 4);
    float* y_bb = (float*)alloc((size_t)N_BUS * H * 4);
    float* y_bg = (float*)alloc((size_t)N_BUS * H * 4);
    float* y_gb = (float*)alloc((size_t)N_GEN * H * 4);
    float* h_bus = (float*)alloc((size_t)N_BUS * H * 4);
    float* h_gen = (float*)alloc((size_t)N_GEN * H * 4);
    float* W1b = (float*)alloc(64 * 96 * 4);
    float* B1b = (float*)alloc(96 * 4);
    float* W1g = (float*)alloc(64 * 64 * 4);
    float* B1g = (float*)alloc(64 * 4);
    float* W2b = (float*)alloc(32 * 96 * 4);
    float* B2b = (float*)alloc(96 * 4);
    float* W2g = (float*)alloc(32 * 64 * 4);
    float* B2g = (float*)alloc(64 * 4);

    // Pair buffers alias y_* (CSR build completes before transforms write y).
    unsigned* p_bb = (unsigned*)y_bb;  // 6.4 MB <= 25.6 MB
    unsigned* p_gb = (unsigned*)y_bg;  // 1.6 MB
    unsigned* p_bg = (unsigned*)y_gb;  // 1.6 MB

    // Fold weights.
    prep_kernel<<<32, 256, 0, stream>>>(
        l1_bb_Wl, l1_bb_bl, l1_bb_Wr, l1_gb_Wl, l1_gb_bl, l1_gb_Wr,
        l1_bg_Wl, l1_bg_bl, l1_bg_Wr, l2_bb_Wl, l2_bb_bl, l2_bb_Wr,
        l2_gb_Wl, l2_gb_bl, l2_gb_Wr, l2_bg_Wl, l2_bg_bl, l2_bg_Wr,
        W1b, B1b, W1g, B1g, W2b, B2b, W2g, B2g);

    // cursors are contiguous: one memset.
    hipMemsetAsync(cur_bb, 0, 3 * NBINS * 4, stream);

    auto build_csr = [&](const int* src, const int* dst, int nE, int nDst,
                         unsigned* cur, unsigned* pairs, unsigned* rs, unsigned* esrc) {
        int hb = (nE + 255) / 256; if (hb > 256) hb = 256;
        coarse_hist_kernel<<<hb, 256, 0, stream>>>(dst, nE, cur);
        scan1024_kernel<<<1, 256, 0, stream>>>(cur);
        partition_kernel<<<(nE + 256 * EPT - 1) / (256 * EPT), 256, 0, stream>>>(src, dst, nE, cur, pairs);
        fine_csr_kernel<<<(nDst + 255) / 256, 256, 0, stream>>>(cur, pairs, rs, esrc, nDst);
    };
    build_csr(src_bb, dst_bb, E_BB, N_BUS, cur_bb, p_bb, rs_bb, e_bb);
    build_csr(src_gb, dst_gb, E_GB, N_BUS, cur_gb, p_gb, rs_gb, e_gb);
    build_csr(src_bg, dst_bg, E_BG, N_GEN, cur_bg, p_bg, rs_bg, e_bg);

    const int gb_bus = (N_BUS + 255) / 256;
    const int gb_gen = (N_GEN + 255) / 256;
    const int gp_bus = (N_BUS * 8 + 255) / 256;
    const int gp_gen = (N_GEN * 8 + 255) / 256;

    // ---- Layer 1 ----
    transform3_kernel<64, 96, false, 2><<<gb_bus, 256, 0, stream>>>(
        x_bus, N_BUS, W1b, B1b, y_bb, y_bg, h_bus);
    transform3_kernel<64, 64, false, 2><<<gb_gen, 256, 0, stream>>>(
        x_gen, N_GEN, W1g, B1g, y_gb, nullptr, h_gen);
    pull_kernel<true><<<gp_bus, 256, 0, stream>>>(rs_bb, e_bb, y_bb, rs_gb, e_gb, y_gb, h_bus, N_BUS);
    pull_kernel<false><<<gp_gen, 256, 0, stream>>>(rs_bg, e_bg, y_bg, nullptr, nullptr, nullptr, h_gen, N_GEN);

    // ---- Layer 2 (relu on load; root written in-place over h_*) ----
    transform3_kernel<32, 96, true, 3><<<gb_bus, 256, 0, stream>>>(
        h_bus, N_BUS, W2b, B2b, y_bb, y_bg, h_bus);
    transform3_kernel<32, 64, true, 3><<<gb_gen, 256, 0, stream>>>(
        h_gen, N_GEN, W2g, B2g, y_gb, nullptr, h_gen);
    pull_kernel<true><<<gp_bus, 256, 0, stream>>>(rs_bb, e_bb, y_bb, rs_gb, e_gb, y_gb, h_bus, N_BUS);
    pull_kernel<false><<<gp_gen, 256, 0, stream>>>(rs_bg, e_bg, y_bg, nullptr, nullptr, nullptr, h_gen, N_GEN);

    // ---- Head ----
    final_kernel<4><<<gb_bus, 256, 0, stream>>>(h_bus, N_BUS, lin0_bus_W, lin0_bus_b,
                                                linf_bus_W, linf_bus_b, (float*)d_out);
    final_kernel<2><<<gb_gen, 256, 0, stream>>>(h_gen, N_GEN, lin0_gen_W, lin0_gen_b,
                                                linf_gen_W, linf_gen_b, (float*)d_out + (size_t)N_BUS * 4);
}

// Round 6
// 473.580 us; speedup vs baseline: 1.2066x; 1.2066x over previous
//
#include <hip/hip_runtime.h>
#include <hip/hip_bf16.h>

#define N_BUS 200000
#define N_GEN 50000
#define E_BB 1600000
#define E_GB 400000
#define E_BG 400000
#define H 32
#define NBINS 1024   // max coarse buckets (>= ceil(200000/256) = 782)
#define EPT 16       // edges per thread in partition (chunk = 4096)

typedef __attribute__((ext_vector_type(8))) short short8;
typedef __attribute__((ext_vector_type(4))) float floatx4;

__device__ inline unsigned short f2bf(float f) {
    __hip_bfloat16 h = __float2bfloat16(f);   // RNE
    return *reinterpret_cast<unsigned short*>(&h);
}
__device__ inline float bf2f(unsigned short u) {
    return __uint_as_float(((unsigned)u) << 16);
}

// ---------------------------------------------------------------------------
// Coarse histogram over 256-dst buckets, LDS-privatized.
__global__ __launch_bounds__(256) void coarse_hist_kernel(const int* __restrict__ dst,
                                                          int nE, unsigned* __restrict__ bcnt) {
    __shared__ unsigned h[NBINS];
    for (int i = threadIdx.x; i < NBINS; i += 256) h[i] = 0;
    __syncthreads();
    for (int e = blockIdx.x * 256 + threadIdx.x; e < nE; e += gridDim.x * 256)
        atomicAdd(&h[(unsigned)dst[e] >> 8], 1u);
    __syncthreads();
    for (int i = threadIdx.x; i < NBINS; i += 256)
        if (h[i]) atomicAdd(&bcnt[i], h[i]);
}

// In-place exclusive scan of exactly 1024 entries, single block (256 thr x 4).
__global__ __launch_bounds__(256) void scan1024_kernel(unsigned* __restrict__ a) {
    __shared__ unsigned sh[256];
    int tid = threadIdx.x;
    int base = tid * 4;
    unsigned v[4], ts = 0;
#pragma unroll
    for (int q = 0; q < 4; q++) { v[q] = a[base + q]; ts += v[q]; }
    sh[tid] = ts;
    __syncthreads();
#pragma unroll
    for (int d = 1; d < 256; d <<= 1) {
        unsigned t = (tid >= d) ? sh[tid - d] : 0u;
        __syncthreads();
        sh[tid] += t;
        __syncthreads();
    }
    unsigned run = sh[tid] - ts;
#pragma unroll
    for (int q = 0; q < 4; q++) { a[base + q] = run; run += v[q]; }
}

// Partition scatter: block-staged chunks, one global atomic per (block,bucket).
__global__ __launch_bounds__(256) void partition_kernel(const int* __restrict__ src,
                                                        const int* __restrict__ dst, int nE,
                                                        unsigned* __restrict__ cursor,
                                                        unsigned* __restrict__ pairs) {
    __shared__ unsigned hist[NBINS];
    __shared__ unsigned base[NBINS];
    const int tid = threadIdx.x;
    const int cbase = blockIdx.x * (256 * EPT);

    unsigned es[EPT], ed[EPT];
#pragma unroll
    for (int q = 0; q < EPT; q++) {
        int i = cbase + q * 256 + tid;
        if (i < nE) { es[q] = (unsigned)src[i]; ed[q] = (unsigned)dst[i]; }
        else ed[q] = 0xFFFFFFFFu;
    }
    for (int i = tid; i < NBINS; i += 256) hist[i] = 0;
    __syncthreads();
#pragma unroll
    for (int q = 0; q < EPT; q++)
        if (ed[q] != 0xFFFFFFFFu) atomicAdd(&hist[ed[q] >> 8], 1u);
    __syncthreads();
    for (int i = tid; i < NBINS; i += 256) {
        unsigned c = hist[i];
        base[i] = c ? atomicAdd(&cursor[i], c) : 0u;
        hist[i] = 0;  // reuse as local cursor
    }
    __syncthreads();
#pragma unroll
    for (int q = 0; q < EPT; q++) {
        if (ed[q] != 0xFFFFFFFFu) {
            unsigned b = ed[q] >> 8;
            unsigned off = atomicAdd(&hist[b], 1u);
            pairs[base[b] + off] = ((ed[q] & 255u) << 24) | es[q];
        }
    }
}

// Fine CSR: one block per coarse bucket -> row ends (rs) + dst-sorted srcs.
__global__ __launch_bounds__(256) void fine_csr_kernel(const unsigned* __restrict__ cursor,
                                                       const unsigned* __restrict__ pairs,
                                                       unsigned* __restrict__ rs,
                                                       unsigned* __restrict__ esrc, int nDst) {
    __shared__ unsigned cnt[256];
    __shared__ unsigned sh[256];
    const int tid = threadIdx.x;
    const int b = blockIdx.x;
    const unsigned start = b ? cursor[b - 1] : 0u;
    const unsigned end = cursor[b];

    cnt[tid] = 0;
    __syncthreads();
    for (unsigned k = start + tid; k < end; k += 256)
        atomicAdd(&cnt[pairs[k] >> 24], 1u);
    __syncthreads();
    unsigned c = cnt[tid];
    sh[tid] = c;
    __syncthreads();
#pragma unroll
    for (int d = 1; d < 256; d <<= 1) {
        unsigned t = (tid >= d) ? sh[tid - d] : 0u;
        __syncthreads();
        sh[tid] += t;
        __syncthreads();
    }
    int gd = b * 256 + tid;
    if (gd < nDst) rs[gd] = start + sh[tid];  // inclusive row end
    cnt[tid] = sh[tid] - c;                   // exclusive offset -> cursor
    __syncthreads();
    for (unsigned k = start + tid; k < end; k += 256) {
        unsigned p = pairs[k];
        unsigned off = atomicAdd(&cnt[p >> 24], 1u);
        esrc[start + off] = p & 0x00FFFFFFu;
    }
}

// ---------------------------------------------------------------------------
// Prep: build bf16 MFMA B-fragment buffers + fused bias vectors.
// Logical W[k][n]: bus (NOUT=96): [Wl_bb | Wl_bg | Wr_bb+Wr_gb];
//                  gen (NOUT=64): [Wl_gb | Wr_bg].
// Fragment order: Wf[((kt*NTN+nt)*64 + lane)*8 + j] = bf16(W[kt*32+quad*8+j][nt*16+(lane&15)])
// so each lane's short8 for tile (kt,nt) is one contiguous 16B load.
__global__ __launch_bounds__(256) void prep_kernel(
    const float* __restrict__ l1_bb_Wl, const float* __restrict__ l1_bb_bl, const float* __restrict__ l1_bb_Wr,
    const float* __restrict__ l1_gb_Wl, const float* __restrict__ l1_gb_bl, const float* __restrict__ l1_gb_Wr,
    const float* __restrict__ l1_bg_Wl, const float* __restrict__ l1_bg_bl, const float* __restrict__ l1_bg_Wr,
    const float* __restrict__ l2_bb_Wl, const float* __restrict__ l2_bb_bl, const float* __restrict__ l2_bb_Wr,
    const float* __restrict__ l2_gb_Wl, const float* __restrict__ l2_gb_bl, const float* __restrict__ l2_gb_Wr,
    const float* __restrict__ l2_bg_Wl, const float* __restrict__ l2_bg_bl, const float* __restrict__ l2_bg_Wr,
    unsigned short* __restrict__ Wf1b, float* __restrict__ B1b,
    unsigned short* __restrict__ Wf1g, float* __restrict__ B1g,
    unsigned short* __restrict__ Wf2b, float* __restrict__ B2b,
    unsigned short* __restrict__ Wf2g, float* __restrict__ B2g)
{
    int t0 = blockIdx.x * 256 + threadIdx.x;
    int NT = gridDim.x * 256;

    // L1 bus: KT=2, NTN=6
    for (int f = t0; f < 2 * 6 * 64 * 8; f += NT) {
        int j = f & 7, l = (f >> 3) & 63, tile = f >> 9;
        int nt = tile % 6, kt = tile / 6;
        int k = kt * 32 + (l >> 4) * 8 + j, n = nt * 16 + (l & 15);
        float v;
        if (n < 32) v = l1_bb_Wl[k * 32 + n];
        else if (n < 64) v = l1_bg_Wl[k * 32 + n - 32];
        else v = l1_bb_Wr[k * 32 + n - 64] + l1_gb_Wr[k * 32 + n - 64];
        Wf1b[f] = f2bf(v);
    }
    // L1 gen: KT=2, NTN=4
    for (int f = t0; f < 2 * 4 * 64 * 8; f += NT) {
        int j = f & 7, l = (f >> 3) & 63, tile = f >> 9;
        int nt = tile % 4, kt = tile / 4;
        int k = kt * 32 + (l >> 4) * 8 + j, n = nt * 16 + (l & 15);
        float v = (n < 32) ? l1_gb_Wl[k * 32 + n] : l1_bg_Wr[k * 32 + n - 32];
        Wf1g[f] = f2bf(v);
    }
    // L2 bus: KT=1, NTN=6
    for (int f = t0; f < 6 * 64 * 8; f += NT) {
        int j = f & 7, l = (f >> 3) & 63, nt = f >> 9;
        int k = (l >> 4) * 8 + j, n = nt * 16 + (l & 15);
        float v;
        if (n < 32) v = l2_bb_Wl[k * 32 + n];
        else if (n < 64) v = l2_bg_Wl[k * 32 + n - 32];
        else v = l2_bb_Wr[k * 32 + n - 64] + l2_gb_Wr[k * 32 + n - 64];
        Wf2b[f] = f2bf(v);
    }
    // L2 gen: KT=1, NTN=4
    for (int f = t0; f < 4 * 64 * 8; f += NT) {
        int j = f & 7, l = (f >> 3) & 63, nt = f >> 9;
        int k = (l >> 4) * 8 + j, n = nt * 16 + (l & 15);
        float v = (n < 32) ? l2_gb_Wl[k * 32 + n] : l2_bg_Wr[k * 32 + n - 32];
        Wf2g[f] = f2bf(v);
    }
    if (t0 < 96) {
        B1b[t0] = (t0 < 64) ? 0.0f : l1_bb_bl[t0 - 64] + l1_gb_bl[t0 - 64];
        B2b[t0] = (t0 < 64) ? 0.0f : l2_bb_bl[t0 - 64] + l2_gb_bl[t0 - 64];
    }
    if (t0 < 64) {
        B1g[t0] = (t0 < 32) ? 0.0f : l1_bg_bl[t0 - 32];
        B2g[t0] = (t0 < 32) ? 0.0f : l2_bg_bl[t0 - 32];
    }
}

// ---------------------------------------------------------------------------
// Node transform v4: bf16 MFMA GEMM [256 x K] @ [K x NOUT] per block.
//  - B-fragments (weights) pre-swizzled in global, loaded once into VGPRs.
//  - x staged to LDS as bf16 (row stride K+8 shorts: conflict-free b128 A-frags).
//  - acc = C-frags (16x16x32), init from bias vector.
//  - epilogue: LDS transpose (stride 34 floats) -> coalesced stores.
// y outputs bf16, h output fp32. x may alias h (block owns its rows; tile is
// fully staged before any store).
template <int K, int NOUT, bool RELU_IN>
__global__ __launch_bounds__(256) void transform4_kernel(
    const float* x, int n,
    const unsigned short* __restrict__ Wf, const float* __restrict__ bias,
    unsigned short* __restrict__ y0, unsigned short* __restrict__ y1, float* h)
{
    constexpr int KT = K / 32, NTN = NOUT / 16, NCH = NOUT / 32;
    constexpr int XS = K + 8;  // shorts
    constexpr int OS = 34;     // floats
    constexpr int XB = 256 * XS * 2, OB = 256 * OS * 4;
    __shared__ __align__(16) char ldsraw[(XB > OB) ? XB : OB];
    short* lx = (short*)ldsraw;
    float* lo = (float*)ldsraw;

    const int tid = threadIdx.x;
    const int base = blockIdx.x * 256;
    const int rows = min(256, n - base);
    const int w = tid >> 6, l = tid & 63, quad = l >> 4, ln = l & 15;

    // B fragments + bias (global loads overlap with staging below)
    short8 bf[KT][NTN];
    const short8* wf8 = (const short8*)Wf;
#pragma unroll
    for (int kt = 0; kt < KT; kt++)
#pragma unroll
        for (int nt = 0; nt < NTN; nt++)
            bf[kt][nt] = wf8[(kt * NTN + nt) * 64 + l];
    float bv[NTN];
#pragma unroll
    for (int nt = 0; nt < NTN; nt++) bv[nt] = bias[nt * 16 + ln];

    // ---- stage x tile (fp32 -> bf16, optional relu) ----
    {
        const float4* xg = (const float4*)(x + (size_t)base * K);
        const int T4 = rows * (K / 4);
        for (int q = tid; q < T4; q += 256) {
            float4 v = xg[q];
            if (RELU_IN) {
                v.x = fmaxf(v.x, 0.f); v.y = fmaxf(v.y, 0.f);
                v.z = fmaxf(v.z, 0.f); v.w = fmaxf(v.w, 0.f);
            }
            int r = q / (K / 4), c = (q % (K / 4)) * 4;
            short4 s4;
            s4.x = (short)f2bf(v.x); s4.y = (short)f2bf(v.y);
            s4.z = (short)f2bf(v.z); s4.w = (short)f2bf(v.w);
            *(short4*)&lx[r * XS + c] = s4;
        }
    }
    __syncthreads();

    // ---- MFMA: wave w owns rows [w*64, w*64+64) ----
    floatx4 acc[4][NTN];
#pragma unroll
    for (int mt = 0; mt < 4; mt++)
#pragma unroll
        for (int nt = 0; nt < NTN; nt++) {
            floatx4 c0 = {bv[nt], bv[nt], bv[nt], bv[nt]};
            acc[mt][nt] = c0;
        }
#pragma unroll
    for (int mt = 0; mt < 4; mt++) {
        const int row = w * 64 + mt * 16 + ln;  // A[m = lane&15][k = quad*8+j]
#pragma unroll
        for (int kt = 0; kt < KT; kt++) {
            short8 af = *(const short8*)&lx[row * XS + kt * 32 + quad * 8];
#pragma unroll
            for (int nt = 0; nt < NTN; nt++)
                acc[mt][nt] = __builtin_amdgcn_mfma_f32_16x16x32_bf16(
                    af, bf[kt][nt], acc[mt][nt], 0, 0, 0);
        }
    }

    // ---- epilogue: per-32-col chunk LDS transpose -> coalesced stores ----
    // C/D layout: col = lane&15, row = quad*4 + reg.
#pragma unroll
    for (int c = 0; c < NCH; c++) {
        __syncthreads();
#pragma unroll
        for (int mt = 0; mt < 4; mt++)
#pragma unroll
            for (int d = 0; d < 2; d++) {
                int nt = 2 * c + d;
#pragma unroll
                for (int r = 0; r < 4; r++)
                    lo[(w * 64 + mt * 16 + quad * 4 + r) * OS + d * 16 + ln] = acc[mt][nt][r];
            }
        __syncthreads();
        const int T4 = rows * 8;
        if (c == NCH - 1) {  // h chunk, fp32
            float* og = h + (size_t)base * 32;
            for (int q = tid; q < T4; q += 256) {
                int r = q >> 3, cc = (q & 7) * 4;
                const float* p = &lo[r * OS + cc];
                *(float4*)(og + q * 4) = make_float4(p[0], p[1], p[2], p[3]);
            }
        } else {  // y chunk, bf16
            unsigned short* og = ((c == 0) ? y0 : y1) + (size_t)base * 32;
            for (int q = tid; q < T4; q += 256) {
                int r = q >> 3, cc = (q & 7) * 4;
                const float* p = &lo[r * OS + cc];
                short4 s4;
                s4.x = (short)f2bf(p[0]); s4.y = (short)f2bf(p[1]);
                s4.z = (short)f2bf(p[2]); s4.w = (short)f2bf(p[3]);
                *(short4*)(og + q * 4) = s4;
            }
        }
    }
}

// ---------------------------------------------------------------------------
// Pull aggregation (bf16 y): h[node] += mean_A(yA[srcs]) (+ mean_B(yB[srcs])).
// 8 threads per node, 4 cols (8B bf16) per thread. rs row i: [rs[i-1], rs[i]).
template <bool HASB>
__global__ __launch_bounds__(256) void pull_kernel(
    const unsigned* __restrict__ rsA, const unsigned* __restrict__ eA, const unsigned short* __restrict__ yA,
    const unsigned* __restrict__ rsB, const unsigned* __restrict__ eB, const unsigned short* __restrict__ yB,
    float* __restrict__ h, int n)
{
    unsigned t = blockIdx.x * 256u + threadIdx.x;
    unsigned node = t >> 3;
    int j = (int)(t & 7u) * 4;
    if (node >= (unsigned)n) return;

    float4 r = *(const float4*)(h + (size_t)node * H + j);  // root term

    {
        unsigned k0 = node ? rsA[node - 1] : 0u;
        unsigned k1 = rsA[node];
        float4 acc = make_float4(0.f, 0.f, 0.f, 0.f);
        for (unsigned k = k0; k < k1; ++k) {
            unsigned s = eA[k];
            const ushort4 v = *(const ushort4*)(yA + (size_t)s * H + j);
            acc.x += bf2f(v.x); acc.y += bf2f(v.y); acc.z += bf2f(v.z); acc.w += bf2f(v.w);
        }
        unsigned c = k1 - k0;
        float inv = 1.0f / (float)(c > 1u ? c : 1u);
        r.x += acc.x * inv; r.y += acc.y * inv; r.z += acc.z * inv; r.w += acc.w * inv;
    }
    if (HASB) {
        unsigned k0 = node ? rsB[node - 1] : 0u;
        unsigned k1 = rsB[node];
        float4 acc = make_float4(0.f, 0.f, 0.f, 0.f);
        for (unsigned k = k0; k < k1; ++k) {
            unsigned s = eB[k];
            const ushort4 v = *(const ushort4*)(yB + (size_t)s * H + j);
            acc.x += bf2f(v.x); acc.y += bf2f(v.y); acc.z += bf2f(v.z); acc.w += bf2f(v.w);
        }
        unsigned c = k1 - k0;
        float inv = 1.0f / (float)(c > 1u ? c : 1u);
        r.x += acc.x * inv; r.y += acc.y * inv; r.z += acc.z * inv; r.w += acc.w * inv;
    }

    *(float4*)(h + (size_t)node * H + j) = r;
}

// ---------------------------------------------------------------------------
// Head: out = relu(h) @ (lin0_W @ linf_W) + (lin0_b @ linf_W + linf_b).
template <int DOUT>
__global__ __launch_bounds__(256) void final_kernel(
    const float* __restrict__ h, int n,
    const float* __restrict__ lin0W, const float* __restrict__ lin0b,
    const float* __restrict__ linfW, const float* __restrict__ linfb,
    float* __restrict__ out)
{
    __shared__ float we[H * DOUT];
    __shared__ float be[DOUT];
    if (threadIdx.x < H * DOUT) {
        int k = threadIdx.x / DOUT, c = threadIdx.x % DOUT;
        float s = 0.0f;
        for (int m = 0; m < H; m++) s += lin0W[k * H + m] * linfW[m * DOUT + c];
        we[threadIdx.x] = s;
    }
    if (threadIdx.x >= 128 && threadIdx.x < 128 + DOUT) {
        int c = threadIdx.x - 128;
        float s = linfb[c];
        for (int m = 0; m < H; m++) s += lin0b[m] * linfW[m * DOUT + c];
        be[c] = s;
    }
    __syncthreads();

    int i = blockIdx.x * 256 + threadIdx.x;
    if (i >= n) return;

    const float4* hp = (const float4*)(h + (size_t)i * H);
    float acc[DOUT];
#pragma unroll
    for (int c = 0; c < DOUT; c++) acc[c] = be[c];
#pragma unroll
    for (int q = 0; q < H / 4; q++) {
        float4 v = hp[q];
        float vs[4] = {fmaxf(v.x, 0.0f), fmaxf(v.y, 0.0f), fmaxf(v.z, 0.0f), fmaxf(v.w, 0.0f)};
#pragma unroll
        for (int r = 0; r < 4; r++) {
            int k = q * 4 + r;
#pragma unroll
            for (int c = 0; c < DOUT; c++) acc[c] = fmaf(vs[r], we[k * DOUT + c], acc[c]);
        }
    }
    if constexpr (DOUT == 4) {
        *(float4*)(out + (size_t)i * 4) = make_float4(acc[0], acc[1], acc[2], acc[3]);
    } else {
        *(float2*)(out + (size_t)i * 2) = make_float2(acc[0], acc[1]);
    }
}

// ---------------------------------------------------------------------------
extern "C" void kernel_launch(void* const* d_in, const int* in_sizes, int n_in,
                              void* d_out, int out_size, void* d_ws, size_t ws_size,
                              hipStream_t stream) {
    const float* x_bus = (const float*)d_in[0];
    const float* x_gen = (const float*)d_in[1];
    const int* src_bb = (const int*)d_in[2];
    const int* dst_bb = (const int*)d_in[3];
    const int* src_gb = (const int*)d_in[4];
    const int* dst_gb = (const int*)d_in[5];
    const int* src_bg = (const int*)d_in[6];
    const int* dst_bg = (const int*)d_in[7];
    const float* l1_bb_Wl = (const float*)d_in[8];
    const float* l1_bb_bl = (const float*)d_in[9];
    const float* l1_bb_Wr = (const float*)d_in[10];
    const float* l1_gb_Wl = (const float*)d_in[11];
    const float* l1_gb_bl = (const float*)d_in[12];
    const float* l1_gb_Wr = (const float*)d_in[13];
    const float* l1_bg_Wl = (const float*)d_in[14];
    const float* l1_bg_bl = (const float*)d_in[15];
    const float* l1_bg_Wr = (const float*)d_in[16];
    const float* l2_bb_Wl = (const float*)d_in[17];
    const float* l2_bb_bl = (const float*)d_in[18];
    const float* l2_bb_Wr = (const float*)d_in[19];
    const float* l2_gb_Wl = (const float*)d_in[20];
    const float* l2_gb_bl = (const float*)d_in[21];
    const float* l2_gb_Wr = (const float*)d_in[22];
    const float* l2_bg_Wl = (const float*)d_in[23];
    const float* l2_bg_bl = (const float*)d_in[24];
    const float* l2_bg_Wr = (const float*)d_in[25];
    const float* lin0_bus_W = (const float*)d_in[26];
    const float* lin0_bus_b = (const float*)d_in[27];
    const float* linf_bus_W = (const float*)d_in[28];
    const float* linf_bus_b = (const float*)d_in[29];
    const float* lin0_gen_W = (const float*)d_in[30];
    const float* lin0_gen_b = (const float*)d_in[31];
    const float* linf_gen_W = (const float*)d_in[32];
    const float* linf_gen_b = (const float*)d_in[33];

    // Workspace layout (~75 MB).
    char* ws = (char*)d_ws;
    size_t off = 0;
    auto alloc = [&](size_t bytes) {
        char* p = ws + off;
        off += (bytes + 255) & ~(size_t)255;
        return p;
    };
    unsigned* rs_bb = (unsigned*)alloc((size_t)N_BUS * 4);
    unsigned* rs_gb = (unsigned*)alloc((size_t)N_BUS * 4);
    unsigned* rs_bg = (unsigned*)alloc((size_t)N_GEN * 4);
    unsigned* cur_bb = (unsigned*)alloc(NBINS * 4);
    unsigned* cur_gb = (unsigned*)alloc(NBINS * 4);
    unsigned* cur_bg = (unsigned*)alloc(NBINS * 4);
    unsigned* e_bb = (unsigned*)alloc((size_t)E_BB * 4);
    unsigned* e_gb = (unsigned*)alloc((size_t)E_GB * 4);
    unsigned* e_bg = (unsigned*)alloc((size_t)E_BG * 4);
    unsigned short* y_bb = (unsigned short*)alloc((size_t)N_BUS * H * 2);  // bf16
    unsigned short* y_bg = (unsigned short*)alloc((size_t)N_BUS * H * 2);  // bf16
    unsigned short* y_gb = (unsigned short*)alloc((size_t)N_GEN * H * 2);  // bf16
    float* h_bus = (float*)alloc((size_t)N_BUS * H * 4);
    float* h_gen = (float*)alloc((size_t)N_GEN * H * 4);
    unsigned short* Wf1b = (unsigned short*)alloc(2 * 6 * 64 * 8 * 2);
    float* B1b = (float*)alloc(96 * 4);
    unsigned short* Wf1g = (unsigned short*)alloc(2 * 4 * 64 * 8 * 2);
    float* B1g = (float*)alloc(64 * 4);
    unsigned short* Wf2b = (unsigned short*)alloc(6 * 64 * 8 * 2);
    float* B2b = (float*)alloc(96 * 4);
    unsigned short* Wf2g = (unsigned short*)alloc(4 * 64 * 8 * 2);
    float* B2g = (float*)alloc(64 * 4);

    // Pair buffers alias y_* (CSR build completes before transforms write y).
    unsigned* p_bb = (unsigned*)y_bb;  // 6.4 MB <= 12.8 MB
    unsigned* p_gb = (unsigned*)y_bg;  // 1.6 MB <= 12.8 MB
    unsigned* p_bg = (unsigned*)y_gb;  // 1.6 MB <= 3.2 MB

    // Fold weights into MFMA fragment order.
    prep_kernel<<<32, 256, 0, stream>>>(
        l1_bb_Wl, l1_bb_bl, l1_bb_Wr, l1_gb_Wl, l1_gb_bl, l1_gb_Wr,
        l1_bg_Wl, l1_bg_bl, l1_bg_Wr, l2_bb_Wl, l2_bb_bl, l2_bb_Wr,
        l2_gb_Wl, l2_gb_bl, l2_gb_Wr, l2_bg_Wl, l2_bg_bl, l2_bg_Wr,
        Wf1b, B1b, Wf1g, B1g, Wf2b, B2b, Wf2g, B2g);

    // cursors are contiguous: one memset.
    hipMemsetAsync(cur_bb, 0, 3 * NBINS * 4, stream);

    auto build_csr = [&](const int* src, const int* dst, int nE, int nDst,
                         unsigned* cur, unsigned* pairs, unsigned* rs, unsigned* esrc) {
        int hb = (nE + 255) / 256; if (hb > 256) hb = 256;
        coarse_hist_kernel<<<hb, 256, 0, stream>>>(dst, nE, cur);
        scan1024_kernel<<<1, 256, 0, stream>>>(cur);
        partition_kernel<<<(nE + 256 * EPT - 1) / (256 * EPT), 256, 0, stream>>>(src, dst, nE, cur, pairs);
        fine_csr_kernel<<<(nDst + 255) / 256, 256, 0, stream>>>(cur, pairs, rs, esrc, nDst);
    };
    build_csr(src_bb, dst_bb, E_BB, N_BUS, cur_bb, p_bb, rs_bb, e_bb);
    build_csr(src_gb, dst_gb, E_GB, N_BUS, cur_gb, p_gb, rs_gb, e_gb);
    build_csr(src_bg, dst_bg, E_BG, N_GEN, cur_bg, p_bg, rs_bg, e_bg);

    const int gb_bus = (N_BUS + 255) / 256;
    const int gb_gen = (N_GEN + 255) / 256;
    const int gp_bus = (N_BUS * 8 + 255) / 256;
    const int gp_gen = (N_GEN * 8 + 255) / 256;

    // ---- Layer 1 ----
    transform4_kernel<64, 96, false><<<gb_bus, 256, 0, stream>>>(
        x_bus, N_BUS, Wf1b, B1b, y_bb, y_bg, h_bus);
    transform4_kernel<64, 64, false><<<gb_gen, 256, 0, stream>>>(
        x_gen, N_GEN, Wf1g, B1g, y_gb, nullptr, h_gen);
    pull_kernel<true><<<gp_bus, 256, 0, stream>>>(rs_bb, e_bb, y_bb, rs_gb, e_gb, y_gb, h_bus, N_BUS);
    pull_kernel<false><<<gp_gen, 256, 0, stream>>>(rs_bg, e_bg, y_bg, nullptr, nullptr, nullptr, h_gen, N_GEN);

    // ---- Layer 2 (relu on staging; root written in-place over h_*) ----
    transform4_kernel<32, 96, true><<<gb_bus, 256, 0, stream>>>(
        h_bus, N_BUS, Wf2b, B2b, y_bb, y_bg, h_bus);
    transform4_kernel<32, 64, true><<<gb_gen, 256, 0, stream>>>(
        h_gen, N_GEN, Wf2g, B2g, y_gb, nullptr, h_gen);
    pull_kernel<true><<<gp_bus, 256, 0, stream>>>(rs_bb, e_bb, y_bb, rs_gb, e_gb, y_gb, h_bus, N_BUS);
    pull_kernel<false><<<gp_gen, 256, 0, stream>>>(rs_bg, e_bg, y_bg, nullptr, nullptr, nullptr, h_gen, N_GEN);

    // ---- Head ----
    final_kernel<4><<<gb_bus, 256, 0, stream>>>(h_bus, N_BUS, lin0_bus_W, lin0_bus_b,
                                                linf_bus_W, linf_bus_b, (float*)d_out);
    final_kernel<2><<<gb_gen, 256, 0, stream>>>(h_gen, N_GEN, lin0_gen_W, lin0_gen_b,
                                                linf_gen_W, linf_gen_b, (float*)d_out + (size_t)N_BUS * 4);
}

// Round 7
// 449.478 us; speedup vs baseline: 1.2713x; 1.0536x over previous
//
#include <hip/hip_runtime.h>
#include <hip/hip_bf16.h>

#define N_BUS 200000
#define N_GEN 50000
#define E_BB 1600000
#define E_GB 400000
#define E_BG 400000
#define H 32
#define NBINS 1024   // max coarse buckets (>= ceil(200000/256) = 782)
#define EPT 16       // edges per thread in partition (chunk = 4096)

typedef __attribute__((ext_vector_type(8))) short short8;
typedef __attribute__((ext_vector_type(4))) float floatx4;

__device__ inline unsigned short f2bf(float f) {
    __hip_bfloat16 h = __float2bfloat16(f);   // RNE
    return *reinterpret_cast<unsigned short*>(&h);
}
__device__ inline float bf2f(unsigned short u) {
    return __uint_as_float(((unsigned)u) << 16);
}

// ---------------------------------------------------------------------------
// Coarse histogram over 256-dst buckets, LDS-privatized.
__global__ __launch_bounds__(256) void coarse_hist_kernel(const int* __restrict__ dst,
                                                          int nE, unsigned* __restrict__ bcnt) {
    __shared__ unsigned h[NBINS];
    for (int i = threadIdx.x; i < NBINS; i += 256) h[i] = 0;
    __syncthreads();
    for (int e = blockIdx.x * 256 + threadIdx.x; e < nE; e += gridDim.x * 256)
        atomicAdd(&h[(unsigned)dst[e] >> 8], 1u);
    __syncthreads();
    for (int i = threadIdx.x; i < NBINS; i += 256)
        if (h[i]) atomicAdd(&bcnt[i], h[i]);
}

// In-place exclusive scan of exactly 1024 entries, single block (256 thr x 4).
__global__ __launch_bounds__(256) void scan1024_kernel(unsigned* __restrict__ a) {
    __shared__ unsigned sh[256];
    int tid = threadIdx.x;
    int base = tid * 4;
    unsigned v[4], ts = 0;
#pragma unroll
    for (int q = 0; q < 4; q++) { v[q] = a[base + q]; ts += v[q]; }
    sh[tid] = ts;
    __syncthreads();
#pragma unroll
    for (int d = 1; d < 256; d <<= 1) {
        unsigned t = (tid >= d) ? sh[tid - d] : 0u;
        __syncthreads();
        sh[tid] += t;
        __syncthreads();
    }
    unsigned run = sh[tid] - ts;
#pragma unroll
    for (int q = 0; q < 4; q++) { a[base + q] = run; run += v[q]; }
}

// Partition scatter: block-staged chunks, one global atomic per (block,bucket).
__global__ __launch_bounds__(256) void partition_kernel(const int* __restrict__ src,
                                                        const int* __restrict__ dst, int nE,
                                                        unsigned* __restrict__ cursor,
                                                        unsigned* __restrict__ pairs) {
    __shared__ unsigned hist[NBINS];
    __shared__ unsigned base[NBINS];
    const int tid = threadIdx.x;
    const int cbase = blockIdx.x * (256 * EPT);

    unsigned es[EPT], ed[EPT];
#pragma unroll
    for (int q = 0; q < EPT; q++) {
        int i = cbase + q * 256 + tid;
        if (i < nE) { es[q] = (unsigned)src[i]; ed[q] = (unsigned)dst[i]; }
        else ed[q] = 0xFFFFFFFFu;
    }
    for (int i = tid; i < NBINS; i += 256) hist[i] = 0;
    __syncthreads();
#pragma unroll
    for (int q = 0; q < EPT; q++)
        if (ed[q] != 0xFFFFFFFFu) atomicAdd(&hist[ed[q] >> 8], 1u);
    __syncthreads();
    for (int i = tid; i < NBINS; i += 256) {
        unsigned c = hist[i];
        base[i] = c ? atomicAdd(&cursor[i], c) : 0u;
        hist[i] = 0;  // reuse as local cursor
    }
    __syncthreads();
#pragma unroll
    for (int q = 0; q < EPT; q++) {
        if (ed[q] != 0xFFFFFFFFu) {
            unsigned b = ed[q] >> 8;
            unsigned off = atomicAdd(&hist[b], 1u);
            pairs[base[b] + off] = ((ed[q] & 255u) << 24) | es[q];
        }
    }
}

// Fine CSR: one block per coarse bucket -> row ends (rs) + dst-sorted srcs.
__global__ __launch_bounds__(256) void fine_csr_kernel(const unsigned* __restrict__ cursor,
                                                       const unsigned* __restrict__ pairs,
                                                       unsigned* __restrict__ rs,
                                                       unsigned* __restrict__ esrc, int nDst) {
    __shared__ unsigned cnt[256];
    __shared__ unsigned sh[256];
    const int tid = threadIdx.x;
    const int b = blockIdx.x;
    const unsigned start = b ? cursor[b - 1] : 0u;
    const unsigned end = cursor[b];

    cnt[tid] = 0;
    __syncthreads();
    for (unsigned k = start + tid; k < end; k += 256)
        atomicAdd(&cnt[pairs[k] >> 24], 1u);
    __syncthreads();
    unsigned c = cnt[tid];
    sh[tid] = c;
    __syncthreads();
#pragma unroll
    for (int d = 1; d < 256; d <<= 1) {
        unsigned t = (tid >= d) ? sh[tid - d] : 0u;
        __syncthreads();
        sh[tid] += t;
        __syncthreads();
    }
    int gd = b * 256 + tid;
    if (gd < nDst) rs[gd] = start + sh[tid];  // inclusive row end
    cnt[tid] = sh[tid] - c;                   // exclusive offset -> cursor
    __syncthreads();
    for (unsigned k = start + tid; k < end; k += 256) {
        unsigned p = pairs[k];
        unsigned off = atomicAdd(&cnt[p >> 24], 1u);
        esrc[start + off] = p & 0x00FFFFFFu;
    }
}

// ---------------------------------------------------------------------------
// Prep: build bf16 MFMA B-fragment buffers + fused bias vectors.
// Logical W[k][n]: bus (NOUT=96): [Wl_bb | Wl_bg | Wr_bb+Wr_gb];
//                  gen (NOUT=64): [Wl_gb | Wr_bg].
// Fragment order: Wf[((kt*NTN+nt)*64 + lane)*8 + j] = bf16(W[kt*32+quad*8+j][nt*16+(lane&15)])
__global__ __launch_bounds__(256) void prep_kernel(
    const float* __restrict__ l1_bb_Wl, const float* __restrict__ l1_bb_bl, const float* __restrict__ l1_bb_Wr,
    const float* __restrict__ l1_gb_Wl, const float* __restrict__ l1_gb_bl, const float* __restrict__ l1_gb_Wr,
    const float* __restrict__ l1_bg_Wl, const float* __restrict__ l1_bg_bl, const float* __restrict__ l1_bg_Wr,
    const float* __restrict__ l2_bb_Wl, const float* __restrict__ l2_bb_bl, const float* __restrict__ l2_bb_Wr,
    const float* __restrict__ l2_gb_Wl, const float* __restrict__ l2_gb_bl, const float* __restrict__ l2_gb_Wr,
    const float* __restrict__ l2_bg_Wl, const float* __restrict__ l2_bg_bl, const float* __restrict__ l2_bg_Wr,
    unsigned short* __restrict__ Wf1b, float* __restrict__ B1b,
    unsigned short* __restrict__ Wf1g, float* __restrict__ B1g,
    unsigned short* __restrict__ Wf2b, float* __restrict__ B2b,
    unsigned short* __restrict__ Wf2g, float* __restrict__ B2g)
{
    int t0 = blockIdx.x * 256 + threadIdx.x;
    int NT = gridDim.x * 256;

    // L1 bus: KT=2, NTN=6
    for (int f = t0; f < 2 * 6 * 64 * 8; f += NT) {
        int j = f & 7, l = (f >> 3) & 63, tile = f >> 9;
        int nt = tile % 6, kt = tile / 6;
        int k = kt * 32 + (l >> 4) * 8 + j, n = nt * 16 + (l & 15);
        float v;
        if (n < 32) v = l1_bb_Wl[k * 32 + n];
        else if (n < 64) v = l1_bg_Wl[k * 32 + n - 32];
        else v = l1_bb_Wr[k * 32 + n - 64] + l1_gb_Wr[k * 32 + n - 64];
        Wf1b[f] = f2bf(v);
    }
    // L1 gen: KT=2, NTN=4
    for (int f = t0; f < 2 * 4 * 64 * 8; f += NT) {
        int j = f & 7, l = (f >> 3) & 63, tile = f >> 9;
        int nt = tile % 4, kt = tile / 4;
        int k = kt * 32 + (l >> 4) * 8 + j, n = nt * 16 + (l & 15);
        float v = (n < 32) ? l1_gb_Wl[k * 32 + n] : l1_bg_Wr[k * 32 + n - 32];
        Wf1g[f] = f2bf(v);
    }
    // L2 bus: KT=1, NTN=6
    for (int f = t0; f < 6 * 64 * 8; f += NT) {
        int j = f & 7, l = (f >> 3) & 63, nt = f >> 9;
        int k = (l >> 4) * 8 + j, n = nt * 16 + (l & 15);
        float v;
        if (n < 32) v = l2_bb_Wl[k * 32 + n];
        else if (n < 64) v = l2_bg_Wl[k * 32 + n - 32];
        else v = l2_bb_Wr[k * 32 + n - 64] + l2_gb_Wr[k * 32 + n - 64];
        Wf2b[f] = f2bf(v);
    }
    // L2 gen: KT=1, NTN=4
    for (int f = t0; f < 4 * 64 * 8; f += NT) {
        int j = f & 7, l = (f >> 3) & 63, nt = f >> 9;
        int k = (l >> 4) * 8 + j, n = nt * 16 + (l & 15);
        float v = (n < 32) ? l2_gb_Wl[k * 32 + n] : l2_bg_Wr[k * 32 + n - 32];
        Wf2g[f] = f2bf(v);
    }
    if (t0 < 96) {
        B1b[t0] = (t0 < 64) ? 0.0f : l1_bb_bl[t0 - 64] + l1_gb_bl[t0 - 64];
        B2b[t0] = (t0 < 64) ? 0.0f : l2_bb_bl[t0 - 64] + l2_gb_bl[t0 - 64];
    }
    if (t0 < 64) {
        B1g[t0] = (t0 < 32) ? 0.0f : l1_bg_bl[t0 - 32];
        B2g[t0] = (t0 < 32) ? 0.0f : l2_bg_bl[t0 - 32];
    }
}

// ---------------------------------------------------------------------------
// Node transform v4: bf16 MFMA GEMM [256 x K] @ [K x NOUT] per block.
template <int K, int NOUT, bool RELU_IN>
__global__ __launch_bounds__(256) void transform4_kernel(
    const float* x, int n,
    const unsigned short* __restrict__ Wf, const float* __restrict__ bias,
    unsigned short* __restrict__ y0, unsigned short* __restrict__ y1, float* h)
{
    constexpr int KT = K / 32, NTN = NOUT / 16, NCH = NOUT / 32;
    constexpr int XS = K + 8;  // shorts
    constexpr int OS = 34;     // floats
    constexpr int XB = 256 * XS * 2, OB = 256 * OS * 4;
    __shared__ __align__(16) char ldsraw[(XB > OB) ? XB : OB];
    short* lx = (short*)ldsraw;
    float* lo = (float*)ldsraw;

    const int tid = threadIdx.x;
    const int base = blockIdx.x * 256;
    const int rows = min(256, n - base);
    const int w = tid >> 6, l = tid & 63, quad = l >> 4, ln = l & 15;

    // B fragments + bias
    short8 bf[KT][NTN];
    const short8* wf8 = (const short8*)Wf;
#pragma unroll
    for (int kt = 0; kt < KT; kt++)
#pragma unroll
        for (int nt = 0; nt < NTN; nt++)
            bf[kt][nt] = wf8[(kt * NTN + nt) * 64 + l];
    float bv[NTN];
#pragma unroll
    for (int nt = 0; nt < NTN; nt++) bv[nt] = bias[nt * 16 + ln];

    // ---- stage x tile (fp32 -> bf16, optional relu) ----
    {
        const float4* xg = (const float4*)(x + (size_t)base * K);
        const int T4 = rows * (K / 4);
        for (int q = tid; q < T4; q += 256) {
            float4 v = xg[q];
            if (RELU_IN) {
                v.x = fmaxf(v.x, 0.f); v.y = fmaxf(v.y, 0.f);
                v.z = fmaxf(v.z, 0.f); v.w = fmaxf(v.w, 0.f);
            }
            int r = q / (K / 4), c = (q % (K / 4)) * 4;
            short4 s4;
            s4.x = (short)f2bf(v.x); s4.y = (short)f2bf(v.y);
            s4.z = (short)f2bf(v.z); s4.w = (short)f2bf(v.w);
            *(short4*)&lx[r * XS + c] = s4;
        }
    }
    __syncthreads();

    // ---- MFMA: wave w owns rows [w*64, w*64+64) ----
    floatx4 acc[4][NTN];
#pragma unroll
    for (int mt = 0; mt < 4; mt++)
#pragma unroll
        for (int nt = 0; nt < NTN; nt++) {
            floatx4 c0 = {bv[nt], bv[nt], bv[nt], bv[nt]};
            acc[mt][nt] = c0;
        }
#pragma unroll
    for (int mt = 0; mt < 4; mt++) {
        const int row = w * 64 + mt * 16 + ln;  // A[m = lane&15][k = quad*8+j]
#pragma unroll
        for (int kt = 0; kt < KT; kt++) {
            short8 af = *(const short8*)&lx[row * XS + kt * 32 + quad * 8];
#pragma unroll
            for (int nt = 0; nt < NTN; nt++)
                acc[mt][nt] = __builtin_amdgcn_mfma_f32_16x16x32_bf16(
                    af, bf[kt][nt], acc[mt][nt], 0, 0, 0);
        }
    }

    // ---- epilogue: per-32-col chunk LDS transpose -> coalesced stores ----
    // C/D layout: col = lane&15, row = quad*4 + reg.
#pragma unroll
    for (int c = 0; c < NCH; c++) {
        __syncthreads();
#pragma unroll
        for (int mt = 0; mt < 4; mt++)
#pragma unroll
            for (int d = 0; d < 2; d++) {
                int nt = 2 * c + d;
#pragma unroll
                for (int r = 0; r < 4; r++)
                    lo[(w * 64 + mt * 16 + quad * 4 + r) * OS + d * 16 + ln] = acc[mt][nt][r];
            }
        __syncthreads();
        const int T4 = rows * 8;
        if (c == NCH - 1) {  // h chunk, fp32
            float* og = h + (size_t)base * 32;
            for (int q = tid; q < T4; q += 256) {
                int r = q >> 3, cc = (q & 7) * 4;
                const float* p = &lo[r * OS + cc];
                *(float4*)(og + q * 4) = make_float4(p[0], p[1], p[2], p[3]);
            }
        } else {  // y chunk, bf16
            unsigned short* og = ((c == 0) ? y0 : y1) + (size_t)base * 32;
            for (int q = tid; q < T4; q += 256) {
                int r = q >> 3, cc = (q & 7) * 4;
                const float* p = &lo[r * OS + cc];
                short4 s4;
                s4.x = (short)f2bf(p[0]); s4.y = (short)f2bf(p[1]);
                s4.z = (short)f2bf(p[2]); s4.w = (short)f2bf(p[3]);
                *(short4*)(og + q * 4) = s4;
            }
        }
    }
}

// ---------------------------------------------------------------------------
// Pull aggregation v2 (bf16 y), 4-way software-pipelined gathers.
// 8 threads per node, 4 cols (8B bf16) per thread. rs row i: [rs[i-1], rs[i]).
// 4 independent accumulator chains keep 4 gathers in flight per lane.
template <bool HASB>
__global__ __launch_bounds__(256) void pull_kernel(
    const unsigned* __restrict__ rsA, const unsigned* __restrict__ eA, const unsigned short* __restrict__ yA,
    const unsigned* __restrict__ rsB, const unsigned* __restrict__ eB, const unsigned short* __restrict__ yB,
    float* __restrict__ h, int n)
{
    unsigned t = blockIdx.x * 256u + threadIdx.x;
    unsigned node = t >> 3;
    int j = (int)(t & 7u) * 4;
    if (node >= (unsigned)n) return;

    float4 r = *(const float4*)(h + (size_t)node * H + j);  // root term

    auto accum_rel = [&](const unsigned* __restrict__ rs, const unsigned* __restrict__ e,
                         const unsigned short* __restrict__ y) {
        unsigned k0 = node ? rs[node - 1] : 0u;
        unsigned k1 = rs[node];
        float4 a0 = make_float4(0.f, 0.f, 0.f, 0.f);
        float4 a1 = make_float4(0.f, 0.f, 0.f, 0.f);
        float4 a2 = make_float4(0.f, 0.f, 0.f, 0.f);
        float4 a3 = make_float4(0.f, 0.f, 0.f, 0.f);
        unsigned k = k0;
        for (; k + 4 <= k1; k += 4) {
            // 4 independent index loads, then 4 independent gathers in flight.
            unsigned s0 = e[k], s1 = e[k + 1], s2 = e[k + 2], s3 = e[k + 3];
            ushort4 v0 = *(const ushort4*)(y + (size_t)s0 * H + j);
            ushort4 v1 = *(const ushort4*)(y + (size_t)s1 * H + j);
            ushort4 v2 = *(const ushort4*)(y + (size_t)s2 * H + j);
            ushort4 v3 = *(const ushort4*)(y + (size_t)s3 * H + j);
            a0.x += bf2f(v0.x); a0.y += bf2f(v0.y); a0.z += bf2f(v0.z); a0.w += bf2f(v0.w);
            a1.x += bf2f(v1.x); a1.y += bf2f(v1.y); a1.z += bf2f(v1.z); a1.w += bf2f(v1.w);
            a2.x += bf2f(v2.x); a2.y += bf2f(v2.y); a2.z += bf2f(v2.z); a2.w += bf2f(v2.w);
            a3.x += bf2f(v3.x); a3.y += bf2f(v3.y); a3.z += bf2f(v3.z); a3.w += bf2f(v3.w);
        }
        for (; k < k1; ++k) {
            unsigned s = e[k];
            const ushort4 v = *(const ushort4*)(y + (size_t)s * H + j);
            a0.x += bf2f(v.x); a0.y += bf2f(v.y); a0.z += bf2f(v.z); a0.w += bf2f(v.w);
        }
        a0.x += a1.x + a2.x + a3.x; a0.y += a1.y + a2.y + a3.y;
        a0.z += a1.z + a2.z + a3.z; a0.w += a1.w + a2.w + a3.w;
        unsigned c = k1 - k0;
        float inv = 1.0f / (float)(c > 1u ? c : 1u);
        r.x += a0.x * inv; r.y += a0.y * inv; r.z += a0.z * inv; r.w += a0.w * inv;
    };

    accum_rel(rsA, eA, yA);
    if (HASB) accum_rel(rsB, eB, yB);

    *(float4*)(h + (size_t)node * H + j) = r;
}

// ---------------------------------------------------------------------------
// Head: out = relu(h) @ (lin0_W @ linf_W) + (lin0_b @ linf_W + linf_b).
template <int DOUT>
__global__ __launch_bounds__(256) void final_kernel(
    const float* __restrict__ h, int n,
    const float* __restrict__ lin0W, const float* __restrict__ lin0b,
    const float* __restrict__ linfW, const float* __restrict__ linfb,
    float* __restrict__ out)
{
    __shared__ float we[H * DOUT];
    __shared__ float be[DOUT];
    if (threadIdx.x < H * DOUT) {
        int k = threadIdx.x / DOUT, c = threadIdx.x % DOUT;
        float s = 0.0f;
        for (int m = 0; m < H; m++) s += lin0W[k * H + m] * linfW[m * DOUT + c];
        we[threadIdx.x] = s;
    }
    if (threadIdx.x >= 128 && threadIdx.x < 128 + DOUT) {
        int c = threadIdx.x - 128;
        float s = linfb[c];
        for (int m = 0; m < H; m++) s += lin0b[m] * linfW[m * DOUT + c];
        be[c] = s;
    }
    __syncthreads();

    int i = blockIdx.x * 256 + threadIdx.x;
    if (i >= n) return;

    const float4* hp = (const float4*)(h + (size_t)i * H);
    float acc[DOUT];
#pragma unroll
    for (int c = 0; c < DOUT; c++) acc[c] = be[c];
#pragma unroll
    for (int q = 0; q < H / 4; q++) {
        float4 v = hp[q];
        float vs[4] = {fmaxf(v.x, 0.0f), fmaxf(v.y, 0.0f), fmaxf(v.z, 0.0f), fmaxf(v.w, 0.0f)};
#pragma unroll
        for (int r = 0; r < 4; r++) {
            int k = q * 4 + r;
#pragma unroll
            for (int c = 0; c < DOUT; c++) acc[c] = fmaf(vs[r], we[k * DOUT + c], acc[c]);
        }
    }
    if constexpr (DOUT == 4) {
        *(float4*)(out + (size_t)i * 4) = make_float4(acc[0], acc[1], acc[2], acc[3]);
    } else {
        *(float2*)(out + (size_t)i * 2) = make_float2(acc[0], acc[1]);
    }
}

// ---------------------------------------------------------------------------
extern "C" void kernel_launch(void* const* d_in, const int* in_sizes, int n_in,
                              void* d_out, int out_size, void* d_ws, size_t ws_size,
                              hipStream_t stream) {
    const float* x_bus = (const float*)d_in[0];
    const float* x_gen = (const float*)d_in[1];
    const int* src_bb = (const int*)d_in[2];
    const int* dst_bb = (const int*)d_in[3];
    const int* src_gb = (const int*)d_in[4];
    const int* dst_gb = (const int*)d_in[5];
    const int* src_bg = (const int*)d_in[6];
    const int* dst_bg = (const int*)d_in[7];
    const float* l1_bb_Wl = (const float*)d_in[8];
    const float* l1_bb_bl = (const float*)d_in[9];
    const float* l1_bb_Wr = (const float*)d_in[10];
    const float* l1_gb_Wl = (const float*)d_in[11];
    const float* l1_gb_bl = (const float*)d_in[12];
    const float* l1_gb_Wr = (const float*)d_in[13];
    const float* l1_bg_Wl = (const float*)d_in[14];
    const float* l1_bg_bl = (const float*)d_in[15];
    const float* l1_bg_Wr = (const float*)d_in[16];
    const float* l2_bb_Wl = (const float*)d_in[17];
    const float* l2_bb_bl = (const float*)d_in[18];
    const float* l2_bb_Wr = (const float*)d_in[19];
    const float* l2_gb_Wl = (const float*)d_in[20];
    const float* l2_gb_bl = (const float*)d_in[21];
    const float* l2_gb_Wr = (const float*)d_in[22];
    const float* l2_bg_Wl = (const float*)d_in[23];
    const float* l2_bg_bl = (const float*)d_in[24];
    const float* l2_bg_Wr = (const float*)d_in[25];
    const float* lin0_bus_W = (const float*)d_in[26];
    const float* lin0_bus_b = (const float*)d_in[27];
    const float* linf_bus_W = (const float*)d_in[28];
    const float* linf_bus_b = (const float*)d_in[29];
    const float* lin0_gen_W = (const float*)d_in[30];
    const float* lin0_gen_b = (const float*)d_in[31];
    const float* linf_gen_W = (const float*)d_in[32];
    const float* linf_gen_b = (const float*)d_in[33];

    // Workspace layout (~75 MB).
    char* ws = (char*)d_ws;
    size_t off = 0;
    auto alloc = [&](size_t bytes) {
        char* p = ws + off;
        off += (bytes + 255) & ~(size_t)255;
        return p;
    };
    unsigned* rs_bb = (unsigned*)alloc((size_t)N_BUS * 4);
    unsigned* rs_gb = (unsigned*)alloc((size_t)N_BUS * 4);
    unsigned* rs_bg = (unsigned*)alloc((size_t)N_GEN * 4);
    unsigned* cur_bb = (unsigned*)alloc(NBINS * 4);
    unsigned* cur_gb = (unsigned*)alloc(NBINS * 4);
    unsigned* cur_bg = (unsigned*)alloc(NBINS * 4);
    unsigned* e_bb = (unsigned*)alloc((size_t)E_BB * 4);
    unsigned* e_gb = (unsigned*)alloc((size_t)E_GB * 4);
    unsigned* e_bg = (unsigned*)alloc((size_t)E_BG * 4);
    unsigned short* y_bb = (unsigned short*)alloc((size_t)N_BUS * H * 2);  // bf16
    unsigned short* y_bg = (unsigned short*)alloc((size_t)N_BUS * H * 2);  // bf16
    unsigned short* y_gb = (unsigned short*)alloc((size_t)N_GEN * H * 2);  // bf16
    float* h_bus = (float*)alloc((size_t)N_BUS * H * 4);
    float* h_gen = (float*)alloc((size_t)N_GEN * H * 4);
    unsigned short* Wf1b = (unsigned short*)alloc(2 * 6 * 64 * 8 * 2);
    float* B1b = (float*)alloc(96 * 4);
    unsigned short* Wf1g = (unsigned short*)alloc(2 * 4 * 64 * 8 * 2);
    float* B1g = (float*)alloc(64 * 4);
    unsigned short* Wf2b = (unsigned short*)alloc(6 * 64 * 8 * 2);
    float* B2b = (float*)alloc(96 * 4);
    unsigned short* Wf2g = (unsigned short*)alloc(4 * 64 * 8 * 2);
    float* B2g = (float*)alloc(64 * 4);

    // Pair buffers alias y_* (CSR build completes before transforms write y).
    unsigned* p_bb = (unsigned*)y_bb;  // 6.4 MB <= 12.8 MB
    unsigned* p_gb = (unsigned*)y_bg;  // 1.6 MB <= 12.8 MB
    unsigned* p_bg = (unsigned*)y_gb;  // 1.6 MB <= 3.2 MB

    // Fold weights into MFMA fragment order.
    prep_kernel<<<32, 256, 0, stream>>>(
        l1_bb_Wl, l1_bb_bl, l1_bb_Wr, l1_gb_Wl, l1_gb_bl, l1_gb_Wr,
        l1_bg_Wl, l1_bg_bl, l1_bg_Wr, l2_bb_Wl, l2_bb_bl, l2_bb_Wr,
        l2_gb_Wl, l2_gb_bl, l2_gb_Wr, l2_bg_Wl, l2_bg_bl, l2_bg_Wr,
        Wf1b, B1b, Wf1g, B1g, Wf2b, B2b, Wf2g, B2g);

    // cursors are contiguous: one memset.
    hipMemsetAsync(cur_bb, 0, 3 * NBINS * 4, stream);

    auto build_csr = [&](const int* src, const int* dst, int nE, int nDst,
                         unsigned* cur, unsigned* pairs, unsigned* rs, unsigned* esrc) {
        int hb = (nE + 255) / 256; if (hb > 256) hb = 256;
        coarse_hist_kernel<<<hb, 256, 0, stream>>>(dst, nE, cur);
        scan1024_kernel<<<1, 256, 0, stream>>>(cur);
        partition_kernel<<<(nE + 256 * EPT - 1) / (256 * EPT), 256, 0, stream>>>(src, dst, nE, cur, pairs);
        fine_csr_kernel<<<(nDst + 255) / 256, 256, 0, stream>>>(cur, pairs, rs, esrc, nDst);
    };
    build_csr(src_bb, dst_bb, E_BB, N_BUS, cur_bb, p_bb, rs_bb, e_bb);
    build_csr(src_gb, dst_gb, E_GB, N_BUS, cur_gb, p_gb, rs_gb, e_gb);
    build_csr(src_bg, dst_bg, E_BG, N_GEN, cur_bg, p_bg, rs_bg, e_bg);

    const int gb_bus = (N_BUS + 255) / 256;
    const int gb_gen = (N_GEN + 255) / 256;
    const int gp_bus = (N_BUS * 8 + 255) / 256;
    const int gp_gen = (N_GEN * 8 + 255) / 256;

    // ---- Layer 1 ----
    transform4_kernel<64, 96, false><<<gb_bus, 256, 0, stream>>>(
        x_bus, N_BUS, Wf1b, B1b, y_bb, y_bg, h_bus);
    transform4_kernel<64, 64, false><<<gb_gen, 256, 0, stream>>>(
        x_gen, N_GEN, Wf1g, B1g, y_gb, nullptr, h_gen);
    pull_kernel<true><<<gp_bus, 256, 0, stream>>>(rs_bb, e_bb, y_bb, rs_gb, e_gb, y_gb, h_bus, N_BUS);
    pull_kernel<false><<<gp_gen, 256, 0, stream>>>(rs_bg, e_bg, y_bg, nullptr, nullptr, nullptr, h_gen, N_GEN);

    // ---- Layer 2 (relu on staging; root written in-place over h_*) ----
    transform4_kernel<32, 96, true><<<gb_bus, 256, 0, stream>>>(
        h_bus, N_BUS, Wf2b, B2b, y_bb, y_bg, h_bus);
    transform4_kernel<32, 64, true><<<gb_gen, 256, 0, stream>>>(
        h_gen, N_GEN, Wf2g, B2g, y_gb, nullptr, h_gen);
    pull_kernel<true><<<gp_bus, 256, 0, stream>>>(rs_bb, e_bb, y_bb, rs_gb, e_gb, y_gb, h_bus, N_BUS);
    pull_kernel<false><<<gp_gen, 256, 0, stream>>>(rs_bg, e_bg, y_bg, nullptr, nullptr, nullptr, h_gen, N_GEN);

    // ---- Head ----
    final_kernel<4><<<gb_bus, 256, 0, stream>>>(h_bus, N_BUS, lin0_bus_W, lin0_bus_b,
                                                linf_bus_W, linf_bus_b, (float*)d_out);
    final_kernel<2><<<gb_gen, 256, 0, stream>>>(h_gen, N_GEN, lin0_gen_W, lin0_gen_b,
                                                linf_gen_W, linf_gen_b, (float*)d_out + (size_t)N_BUS * 4);
}

// Round 8
// 365.769 us; speedup vs baseline: 1.5622x; 1.2289x over previous
//
#include <hip/hip_runtime.h>
#include <hip/hip_bf16.h>

#define N_BUS 200000
#define N_GEN 50000
#define E_BB 1600000
#define E_GB 400000
#define E_BG 400000
#define H 32
#define NBINS 1024   // max coarse buckets (>= ceil(200000/256) = 782)
#define EPT 16       // edges per thread in partition (chunk = 4096)

#define NB_CSR_BUS 782   // ceil(N_BUS/256)
#define NB_CSR_GEN 196   // ceil(N_GEN/256)
#define NB_PART_BB 391   // ceil(E_BB/4096)
#define NB_PART_GB 98
#define NB_PART_BG 98
#define NB_TF_BUS 782    // ceil(N_BUS/256)
#define NB_TF_GEN 196
#define NB_PL_BUS 6250   // ceil(N_BUS/32)
#define NB_PL_GEN 1563   // ceil(N_GEN/32)

typedef __attribute__((ext_vector_type(8))) short short8;
typedef __attribute__((ext_vector_type(4))) float floatx4;

__device__ inline unsigned short f2bf(float f) {
    __hip_bfloat16 h = __float2bfloat16(f);   // RNE
    return *reinterpret_cast<unsigned short*>(&h);
}
__device__ inline float bf2f(unsigned short u) {
    return __uint_as_float(((unsigned)u) << 16);
}

// ---------------------------------------------------------------------------
// CSR phase, merged kernels. Bodies take explicit segment-block index.

__device__ __forceinline__ void hist_body(int blk, int nb, const int* __restrict__ dst,
                                          int nE, unsigned* __restrict__ bcnt) {
    __shared__ unsigned h[NBINS];
    for (int i = threadIdx.x; i < NBINS; i += 256) h[i] = 0;
    __syncthreads();
    for (int e = blk * 256 + threadIdx.x; e < nE; e += nb * 256)
        atomicAdd(&h[(unsigned)dst[e] >> 8], 1u);
    __syncthreads();
    for (int i = threadIdx.x; i < NBINS; i += 256)
        if (h[i]) atomicAdd(&bcnt[i], h[i]);
}

__global__ __launch_bounds__(256) void hist_all_kernel(
    const int* __restrict__ dbb, const int* __restrict__ dgb, const int* __restrict__ dbg,
    unsigned* __restrict__ cbb, unsigned* __restrict__ cgb, unsigned* __restrict__ cbg)
{
    int b = blockIdx.x;
    if (b < 256) hist_body(b, 256, dbb, E_BB, cbb);
    else if (b < 352) hist_body(b - 256, 96, dgb, E_GB, cgb);
    else hist_body(b - 352, 96, dbg, E_BG, cbg);
}

// Exclusive scan of 1024 entries per block; 3 blocks (one per relation).
__global__ __launch_bounds__(256) void scan_all_kernel(unsigned* __restrict__ c0,
                                                       unsigned* __restrict__ c1,
                                                       unsigned* __restrict__ c2) {
    unsigned* a = (blockIdx.x == 0) ? c0 : (blockIdx.x == 1) ? c1 : c2;
    __shared__ unsigned sh[256];
    int tid = threadIdx.x;
    int base = tid * 4;
    unsigned v[4], ts = 0;
#pragma unroll
    for (int q = 0; q < 4; q++) { v[q] = a[base + q]; ts += v[q]; }
    sh[tid] = ts;
    __syncthreads();
#pragma unroll
    for (int d = 1; d < 256; d <<= 1) {
        unsigned t = (tid >= d) ? sh[tid - d] : 0u;
        __syncthreads();
        sh[tid] += t;
        __syncthreads();
    }
    unsigned run = sh[tid] - ts;
#pragma unroll
    for (int q = 0; q < 4; q++) { a[base + q] = run; run += v[q]; }
}

__device__ __forceinline__ void part_body(int blk, const int* __restrict__ src,
                                          const int* __restrict__ dst, int nE,
                                          unsigned* __restrict__ cursor,
                                          unsigned* __restrict__ pairs) {
    __shared__ unsigned hist[NBINS];
    __shared__ unsigned base[NBINS];
    const int tid = threadIdx.x;
    const int cbase = blk * (256 * EPT);

    unsigned es[EPT], ed[EPT];
#pragma unroll
    for (int q = 0; q < EPT; q++) {
        int i = cbase + q * 256 + tid;
        if (i < nE) { es[q] = (unsigned)src[i]; ed[q] = (unsigned)dst[i]; }
        else ed[q] = 0xFFFFFFFFu;
    }
    for (int i = tid; i < NBINS; i += 256) hist[i] = 0;
    __syncthreads();
#pragma unroll
    for (int q = 0; q < EPT; q++)
        if (ed[q] != 0xFFFFFFFFu) atomicAdd(&hist[ed[q] >> 8], 1u);
    __syncthreads();
    for (int i = tid; i < NBINS; i += 256) {
        unsigned c = hist[i];
        base[i] = c ? atomicAdd(&cursor[i], c) : 0u;
        hist[i] = 0;  // reuse as local cursor
    }
    __syncthreads();
#pragma unroll
    for (int q = 0; q < EPT; q++) {
        if (ed[q] != 0xFFFFFFFFu) {
            unsigned b = ed[q] >> 8;
            unsigned off = atomicAdd(&hist[b], 1u);
            pairs[base[b] + off] = ((ed[q] & 255u) << 24) | es[q];
        }
    }
}

__global__ __launch_bounds__(256) void part_all_kernel(
    const int* __restrict__ sbb, const int* __restrict__ dbb, unsigned* __restrict__ cbb, unsigned* __restrict__ pbb,
    const int* __restrict__ sgb, const int* __restrict__ dgb, unsigned* __restrict__ cgb, unsigned* __restrict__ pgb,
    const int* __restrict__ sbg, const int* __restrict__ dbg, unsigned* __restrict__ cbg, unsigned* __restrict__ pbg)
{
    int b = blockIdx.x;
    if (b < NB_PART_BB) part_body(b, sbb, dbb, E_BB, cbb, pbb);
    else if (b < NB_PART_BB + NB_PART_GB) part_body(b - NB_PART_BB, sgb, dgb, E_GB, cgb, pgb);
    else part_body(b - NB_PART_BB - NB_PART_GB, sbg, dbg, E_BG, cbg, pbg);
}

__device__ __forceinline__ void fine_body(int b, const unsigned* __restrict__ cursor,
                                          const unsigned* __restrict__ pairs,
                                          unsigned* __restrict__ rs,
                                          unsigned* __restrict__ esrc, int nDst) {
    __shared__ unsigned cnt[256];
    __shared__ unsigned sh[256];
    const int tid = threadIdx.x;
    const unsigned start = b ? cursor[b - 1] : 0u;
    const unsigned end = cursor[b];

    cnt[tid] = 0;
    __syncthreads();
    for (unsigned k = start + tid; k < end; k += 256)
        atomicAdd(&cnt[pairs[k] >> 24], 1u);
    __syncthreads();
    unsigned c = cnt[tid];
    sh[tid] = c;
    __syncthreads();
#pragma unroll
    for (int d = 1; d < 256; d <<= 1) {
        unsigned t = (tid >= d) ? sh[tid - d] : 0u;
        __syncthreads();
        sh[tid] += t;
        __syncthreads();
    }
    int gd = b * 256 + tid;
    if (gd < nDst) rs[gd] = start + sh[tid];  // inclusive row end
    cnt[tid] = sh[tid] - c;                   // exclusive offset -> cursor
    __syncthreads();
    for (unsigned k = start + tid; k < end; k += 256) {
        unsigned p = pairs[k];
        unsigned off = atomicAdd(&cnt[p >> 24], 1u);
        esrc[start + off] = p & 0x00FFFFFFu;
    }
}

__global__ __launch_bounds__(256) void fine_all_kernel(
    const unsigned* __restrict__ cbb, const unsigned* __restrict__ pbb, unsigned* __restrict__ rsbb, unsigned* __restrict__ ebb,
    const unsigned* __restrict__ cgb, const unsigned* __restrict__ pgb, unsigned* __restrict__ rsgb, unsigned* __restrict__ egb,
    const unsigned* __restrict__ cbg, const unsigned* __restrict__ pbg, unsigned* __restrict__ rsbg, unsigned* __restrict__ ebg)
{
    int b = blockIdx.x;
    if (b < NB_CSR_BUS) fine_body(b, cbb, pbb, rsbb, ebb, N_BUS);
    else if (b < 2 * NB_CSR_BUS) fine_body(b - NB_CSR_BUS, cgb, pgb, rsgb, egb, N_BUS);
    else fine_body(b - 2 * NB_CSR_BUS, cbg, pbg, rsbg, ebg, N_GEN);
}

// ---------------------------------------------------------------------------
// Prep: bf16 MFMA B-fragments + fused biases + fused head matrices.
// Logical W[k][n]: bus (NOUT=96): [Wl_bb | Wl_bg | Wr_bb+Wr_gb];
//                  gen (NOUT=64): [Wl_gb | Wr_bg].
// Fragment order: Wf[((kt*NTN+nt)*64 + lane)*8 + j] = bf16(W[kt*32+quad*8+j][nt*16+(lane&15)])
// Head: We = lin0W @ linfW (fp32), be = lin0b @ linfW + linfb.
__global__ __launch_bounds__(256) void prep_kernel(
    const float* __restrict__ l1_bb_Wl, const float* __restrict__ l1_bb_bl, const float* __restrict__ l1_bb_Wr,
    const float* __restrict__ l1_gb_Wl, const float* __restrict__ l1_gb_bl, const float* __restrict__ l1_gb_Wr,
    const float* __restrict__ l1_bg_Wl, const float* __restrict__ l1_bg_bl, const float* __restrict__ l1_bg_Wr,
    const float* __restrict__ l2_bb_Wl, const float* __restrict__ l2_bb_bl, const float* __restrict__ l2_bb_Wr,
    const float* __restrict__ l2_gb_Wl, const float* __restrict__ l2_gb_bl, const float* __restrict__ l2_gb_Wr,
    const float* __restrict__ l2_bg_Wl, const float* __restrict__ l2_bg_bl, const float* __restrict__ l2_bg_Wr,
    const float* __restrict__ lin0_bus_W, const float* __restrict__ lin0_bus_b,
    const float* __restrict__ linf_bus_W, const float* __restrict__ linf_bus_b,
    const float* __restrict__ lin0_gen_W, const float* __restrict__ lin0_gen_b,
    const float* __restrict__ linf_gen_W, const float* __restrict__ linf_gen_b,
    unsigned short* __restrict__ Wf1b, float* __restrict__ B1b,
    unsigned short* __restrict__ Wf1g, float* __restrict__ B1g,
    unsigned short* __restrict__ Wf2b, float* __restrict__ B2b,
    unsigned short* __restrict__ Wf2g, float* __restrict__ B2g,
    float* __restrict__ WeB, float* __restrict__ beB,
    float* __restrict__ WeG, float* __restrict__ beG)
{
    int t0 = blockIdx.x * 256 + threadIdx.x;
    int NT = gridDim.x * 256;

    // L1 bus: KT=2, NTN=6
    for (int f = t0; f < 2 * 6 * 64 * 8; f += NT) {
        int j = f & 7, l = (f >> 3) & 63, tile = f >> 9;
        int nt = tile % 6, kt = tile / 6;
        int k = kt * 32 + (l >> 4) * 8 + j, n = nt * 16 + (l & 15);
        float v;
        if (n < 32) v = l1_bb_Wl[k * 32 + n];
        else if (n < 64) v = l1_bg_Wl[k * 32 + n - 32];
        else v = l1_bb_Wr[k * 32 + n - 64] + l1_gb_Wr[k * 32 + n - 64];
        Wf1b[f] = f2bf(v);
    }
    // L1 gen: KT=2, NTN=4
    for (int f = t0; f < 2 * 4 * 64 * 8; f += NT) {
        int j = f & 7, l = (f >> 3) & 63, tile = f >> 9;
        int nt = tile % 4, kt = tile / 4;
        int k = kt * 32 + (l >> 4) * 8 + j, n = nt * 16 + (l & 15);
        float v = (n < 32) ? l1_gb_Wl[k * 32 + n] : l1_bg_Wr[k * 32 + n - 32];
        Wf1g[f] = f2bf(v);
    }
    // L2 bus: KT=1, NTN=6
    for (int f = t0; f < 6 * 64 * 8; f += NT) {
        int j = f & 7, l = (f >> 3) & 63, nt = f >> 9;
        int k = (l >> 4) * 8 + j, n = nt * 16 + (l & 15);
        float v;
        if (n < 32) v = l2_bb_Wl[k * 32 + n];
        else if (n < 64) v = l2_bg_Wl[k * 32 + n - 32];
        else v = l2_bb_Wr[k * 32 + n - 64] + l2_gb_Wr[k * 32 + n - 64];
        Wf2b[f] = f2bf(v);
    }
    // L2 gen: KT=1, NTN=4
    for (int f = t0; f < 4 * 64 * 8; f += NT) {
        int j = f & 7, l = (f >> 3) & 63, nt = f >> 9;
        int k = (l >> 4) * 8 + j, n = nt * 16 + (l & 15);
        float v = (n < 32) ? l2_gb_Wl[k * 32 + n] : l2_bg_Wr[k * 32 + n - 32];
        Wf2g[f] = f2bf(v);
    }
    if (t0 < 96) {
        B1b[t0] = (t0 < 64) ? 0.0f : l1_bb_bl[t0 - 64] + l1_gb_bl[t0 - 64];
        B2b[t0] = (t0 < 64) ? 0.0f : l2_bb_bl[t0 - 64] + l2_gb_bl[t0 - 64];
    }
    if (t0 < 64) {
        B1g[t0] = (t0 < 32) ? 0.0f : l1_bg_bl[t0 - 32];
        B2g[t0] = (t0 < 32) ? 0.0f : l2_bg_bl[t0 - 32];
    }
    // Fused head: bus We (32x4) + be(4); gen We (32x2) + be(2)
    if (t0 < 128) {
        int k = t0 >> 2, c = t0 & 3;
        float s = 0.0f;
        for (int m = 0; m < 32; m++) s += lin0_bus_W[k * 32 + m] * linf_bus_W[m * 4 + c];
        WeB[t0] = s;
    }
    if (t0 >= 128 && t0 < 132) {
        int c = t0 - 128;
        float s = linf_bus_b[c];
        for (int m = 0; m < 32; m++) s += lin0_bus_b[m] * linf_bus_W[m * 4 + c];
        beB[c] = s;
    }
    if (t0 >= 132 && t0 < 196) {
        int i = t0 - 132, k = i >> 1, c = i & 1;
        float s = 0.0f;
        for (int m = 0; m < 32; m++) s += lin0_gen_W[k * 32 + m] * linf_gen_W[m * 2 + c];
        WeG[i] = s;
    }
    if (t0 >= 196 && t0 < 198) {
        int c = t0 - 196;
        float s = linf_gen_b[c];
        for (int m = 0; m < 32; m++) s += lin0_gen_b[m] * linf_gen_W[m * 2 + c];
        beG[c] = s;
    }
}

// ---------------------------------------------------------------------------
// Node transform body: bf16 MFMA GEMM [256 x K] @ [K x NOUT] per block.
template <int K, int NOUT, bool RELU_IN>
__device__ __forceinline__ void transform_body(
    int blk, const float* x, int n,
    const unsigned short* __restrict__ Wf, const float* __restrict__ bias,
    unsigned short* __restrict__ y0, unsigned short* __restrict__ y1, float* h,
    char* ldsraw)
{
    constexpr int KT = K / 32, NTN = NOUT / 16, NCH = NOUT / 32;
    constexpr int XS = K + 8;  // shorts
    constexpr int OS = 34;     // floats
    short* lx = (short*)ldsraw;
    float* lo = (float*)ldsraw;

    const int tid = threadIdx.x;
    const int base = blk * 256;
    const int rows = min(256, n - base);
    const int w = tid >> 6, l = tid & 63, quad = l >> 4, ln = l & 15;

    // B fragments + bias
    short8 bf[KT][NTN];
    const short8* wf8 = (const short8*)Wf;
#pragma unroll
    for (int kt = 0; kt < KT; kt++)
#pragma unroll
        for (int nt = 0; nt < NTN; nt++)
            bf[kt][nt] = wf8[(kt * NTN + nt) * 64 + l];
    float bv[NTN];
#pragma unroll
    for (int nt = 0; nt < NTN; nt++) bv[nt] = bias[nt * 16 + ln];

    // ---- stage x tile (fp32 -> bf16, optional relu) ----
    {
        const float4* xg = (const float4*)(x + (size_t)base * K);
        const int T4 = rows * (K / 4);
        for (int q = tid; q < T4; q += 256) {
            float4 v = xg[q];
            if (RELU_IN) {
                v.x = fmaxf(v.x, 0.f); v.y = fmaxf(v.y, 0.f);
                v.z = fmaxf(v.z, 0.f); v.w = fmaxf(v.w, 0.f);
            }
            int r = q / (K / 4), c = (q % (K / 4)) * 4;
            short4 s4;
            s4.x = (short)f2bf(v.x); s4.y = (short)f2bf(v.y);
            s4.z = (short)f2bf(v.z); s4.w = (short)f2bf(v.w);
            *(short4*)&lx[r * XS + c] = s4;
        }
    }
    __syncthreads();

    // ---- MFMA: wave w owns rows [w*64, w*64+64) ----
    floatx4 acc[4][NTN];
#pragma unroll
    for (int mt = 0; mt < 4; mt++)
#pragma unroll
        for (int nt = 0; nt < NTN; nt++) {
            floatx4 c0 = {bv[nt], bv[nt], bv[nt], bv[nt]};
            acc[mt][nt] = c0;
        }
#pragma unroll
    for (int mt = 0; mt < 4; mt++) {
        const int row = w * 64 + mt * 16 + ln;  // A[m = lane&15][k = quad*8+j]
#pragma unroll
        for (int kt = 0; kt < KT; kt++) {
            short8 af = *(const short8*)&lx[row * XS + kt * 32 + quad * 8];
#pragma unroll
            for (int nt = 0; nt < NTN; nt++)
                acc[mt][nt] = __builtin_amdgcn_mfma_f32_16x16x32_bf16(
                    af, bf[kt][nt], acc[mt][nt], 0, 0, 0);
        }
    }

    // ---- epilogue: per-32-col chunk LDS transpose -> coalesced stores ----
    // C/D layout: col = lane&15, row = quad*4 + reg.
#pragma unroll
    for (int c = 0; c < NCH; c++) {
        __syncthreads();
#pragma unroll
        for (int mt = 0; mt < 4; mt++)
#pragma unroll
            for (int d = 0; d < 2; d++) {
                int nt = 2 * c + d;
#pragma unroll
                for (int r = 0; r < 4; r++)
                    lo[(w * 64 + mt * 16 + quad * 4 + r) * OS + d * 16 + ln] = acc[mt][nt][r];
            }
        __syncthreads();
        const int T4 = rows * 8;
        if (c == NCH - 1) {  // h chunk, fp32
            float* og = h + (size_t)base * 32;
            for (int q = tid; q < T4; q += 256) {
                int r = q >> 3, cc = (q & 7) * 4;
                const float* p = &lo[r * OS + cc];
                *(float4*)(og + q * 4) = make_float4(p[0], p[1], p[2], p[3]);
            }
        } else {  // y chunk, bf16
            unsigned short* og = ((c == 0) ? y0 : y1) + (size_t)base * 32;
            for (int q = tid; q < T4; q += 256) {
                int r = q >> 3, cc = (q & 7) * 4;
                const float* p = &lo[r * OS + cc];
                short4 s4;
                s4.x = (short)f2bf(p[0]); s4.y = (short)f2bf(p[1]);
                s4.z = (short)f2bf(p[2]); s4.w = (short)f2bf(p[3]);
                *(short4*)(og + q * 4) = s4;
            }
        }
    }
}

// Merged bus+gen transform launch.
template <int K, bool RELU_IN>
__global__ __launch_bounds__(256) void tf_all_kernel(
    const float* xb, const unsigned short* __restrict__ Wfb, const float* __restrict__ Bb,
    unsigned short* __restrict__ yb0, unsigned short* __restrict__ yb1, float* hb,
    const float* xg, const unsigned short* __restrict__ Wfg, const float* __restrict__ Bg,
    unsigned short* __restrict__ yg0, float* hg)
{
    constexpr int XB = 256 * (K + 8) * 2, OB = 256 * 34 * 4;
    __shared__ __align__(16) char ldsraw[(XB > OB) ? XB : OB];
    int b = blockIdx.x;
    if (b < NB_TF_BUS)
        transform_body<K, 96, RELU_IN>(b, xb, N_BUS, Wfb, Bb, yb0, yb1, hb, ldsraw);
    else
        transform_body<K, 64, RELU_IN>(b - NB_TF_BUS, xg, N_GEN, Wfg, Bg, yg0, nullptr, hg, ldsraw);
}

// ---------------------------------------------------------------------------
// Pull body (bf16 y), 4-way software-pipelined gathers; 8 threads/node.
// FUSE: apply relu + fused head (We 32xD, be D) and write d_out directly
// (no h write). Otherwise write h.
template <bool FUSE>
__device__ __forceinline__ void pull_body(
    int blk, bool hasB, int n,
    const unsigned* __restrict__ rsA, const unsigned* __restrict__ eA, const unsigned short* __restrict__ yA,
    const unsigned* __restrict__ rsB, const unsigned* __restrict__ eB, const unsigned short* __restrict__ yB,
    float* __restrict__ h,
    const float* __restrict__ We, const float* __restrict__ be, int DOUT, float* __restrict__ outp)
{
    const int tid = threadIdx.x;
    unsigned node = blk * 32u + (tid >> 3);
    int j = (tid & 7) * 4;
    if (node >= (unsigned)n) return;

    float4 r = *(const float4*)(h + (size_t)node * H + j);  // root term

    auto accum_rel = [&](const unsigned* __restrict__ rs, const unsigned* __restrict__ e,
                         const unsigned short* __restrict__ y) {
        unsigned k0 = node ? rs[node - 1] : 0u;
        unsigned k1 = rs[node];
        float4 a0 = make_float4(0.f, 0.f, 0.f, 0.f);
        float4 a1 = make_float4(0.f, 0.f, 0.f, 0.f);
        float4 a2 = make_float4(0.f, 0.f, 0.f, 0.f);
        float4 a3 = make_float4(0.f, 0.f, 0.f, 0.f);
        unsigned k = k0;
        for (; k + 4 <= k1; k += 4) {
            unsigned s0 = e[k], s1 = e[k + 1], s2 = e[k + 2], s3 = e[k + 3];
            ushort4 v0 = *(const ushort4*)(y + (size_t)s0 * H + j);
            ushort4 v1 = *(const ushort4*)(y + (size_t)s1 * H + j);
            ushort4 v2 = *(const ushort4*)(y + (size_t)s2 * H + j);
            ushort4 v3 = *(const ushort4*)(y + (size_t)s3 * H + j);
            a0.x += bf2f(v0.x); a0.y += bf2f(v0.y); a0.z += bf2f(v0.z); a0.w += bf2f(v0.w);
            a1.x += bf2f(v1.x); a1.y += bf2f(v1.y); a1.z += bf2f(v1.z); a1.w += bf2f(v1.w);
            a2.x += bf2f(v2.x); a2.y += bf2f(v2.y); a2.z += bf2f(v2.z); a2.w += bf2f(v2.w);
            a3.x += bf2f(v3.x); a3.y += bf2f(v3.y); a3.z += bf2f(v3.z); a3.w += bf2f(v3.w);
        }
        for (; k < k1; ++k) {
            unsigned s = e[k];
            const ushort4 v = *(const ushort4*)(y + (size_t)s * H + j);
            a0.x += bf2f(v.x); a0.y += bf2f(v.y); a0.z += bf2f(v.z); a0.w += bf2f(v.w);
        }
        a0.x += a1.x + a2.x + a3.x; a0.y += a1.y + a2.y + a3.y;
        a0.z += a1.z + a2.z + a3.z; a0.w += a1.w + a2.w + a3.w;
        unsigned c = k1 - k0;
        float inv = 1.0f / (float)(c > 1u ? c : 1u);
        r.x += a0.x * inv; r.y += a0.y * inv; r.z += a0.z * inv; r.w += a0.w * inv;
    };

    accum_rel(rsA, eA, yA);
    if (hasB) accum_rel(rsB, eB, yB);

    if (!FUSE) {
        *(float4*)(h + (size_t)node * H + j) = r;
        return;
    }

    // Fused head: out[node] = relu(hrow) @ We + be, reduced over the 8-lane group.
    float p0 = fmaxf(r.x, 0.f), p1 = fmaxf(r.y, 0.f), p2 = fmaxf(r.z, 0.f), p3 = fmaxf(r.w, 0.f);
    float tot[4];
#pragma unroll
    for (int c = 0; c < 4; c++) {
        if (c < DOUT) {
            tot[c] = p0 * We[(j + 0) * DOUT + c] + p1 * We[(j + 1) * DOUT + c]
                   + p2 * We[(j + 2) * DOUT + c] + p3 * We[(j + 3) * DOUT + c];
        } else tot[c] = 0.f;
    }
#pragma unroll
    for (int mask = 1; mask <= 4; mask <<= 1) {
#pragma unroll
        for (int c = 0; c < 4; c++) tot[c] += __shfl_xor(tot[c], mask);
    }
    if ((tid & 7) == 0) {
        if (DOUT == 4) {
            *(float4*)(outp + (size_t)node * 4) =
                make_float4(tot[0] + be[0], tot[1] + be[1], tot[2] + be[2], tot[3] + be[3]);
        } else {
            *(float2*)(outp + (size_t)node * 2) = make_float2(tot[0] + be[0], tot[1] + be[1]);
        }
    }
}

// Merged bus+gen pull launch.
template <bool FUSE>
__global__ __launch_bounds__(256) void pull_all_kernel(
    const unsigned* __restrict__ rsbb, const unsigned* __restrict__ ebb, const unsigned short* __restrict__ ybb,
    const unsigned* __restrict__ rsgb, const unsigned* __restrict__ egb, const unsigned short* __restrict__ ygb,
    float* __restrict__ hb, const float* __restrict__ WeB, const float* __restrict__ beB,
    const unsigned* __restrict__ rsbg, const unsigned* __restrict__ ebg, const unsigned short* __restrict__ ybg,
    float* __restrict__ hg, const float* __restrict__ WeG, const float* __restrict__ beG,
    float* __restrict__ outp)
{
    int b = blockIdx.x;
    if (b < NB_PL_BUS)
        pull_body<FUSE>(b, true, N_BUS, rsbb, ebb, ybb, rsgb, egb, ygb, hb, WeB, beB, 4, outp);
    else
        pull_body<FUSE>(b - NB_PL_BUS, false, N_GEN, rsbg, ebg, ybg, nullptr, nullptr, nullptr,
                        hg, WeG, beG, 2, outp ? outp + (size_t)N_BUS * 4 : nullptr);
}

// ---------------------------------------------------------------------------
extern "C" void kernel_launch(void* const* d_in, const int* in_sizes, int n_in,
                              void* d_out, int out_size, void* d_ws, size_t ws_size,
                              hipStream_t stream) {
    const float* x_bus = (const float*)d_in[0];
    const float* x_gen = (const float*)d_in[1];
    const int* src_bb = (const int*)d_in[2];
    const int* dst_bb = (const int*)d_in[3];
    const int* src_gb = (const int*)d_in[4];
    const int* dst_gb = (const int*)d_in[5];
    const int* src_bg = (const int*)d_in[6];
    const int* dst_bg = (const int*)d_in[7];
    const float* l1_bb_Wl = (const float*)d_in[8];
    const float* l1_bb_bl = (const float*)d_in[9];
    const float* l1_bb_Wr = (const float*)d_in[10];
    const float* l1_gb_Wl = (const float*)d_in[11];
    const float* l1_gb_bl = (const float*)d_in[12];
    const float* l1_gb_Wr = (const float*)d_in[13];
    const float* l1_bg_Wl = (const float*)d_in[14];
    const float* l1_bg_bl = (const float*)d_in[15];
    const float* l1_bg_Wr = (const float*)d_in[16];
    const float* l2_bb_Wl = (const float*)d_in[17];
    const float* l2_bb_bl = (const float*)d_in[18];
    const float* l2_bb_Wr = (const float*)d_in[19];
    const float* l2_gb_Wl = (const float*)d_in[20];
    const float* l2_gb_bl = (const float*)d_in[21];
    const float* l2_gb_Wr = (const float*)d_in[22];
    const float* l2_bg_Wl = (const float*)d_in[23];
    const float* l2_bg_bl = (const float*)d_in[24];
    const float* l2_bg_Wr = (const float*)d_in[25];
    const float* lin0_bus_W = (const float*)d_in[26];
    const float* lin0_bus_b = (const float*)d_in[27];
    const float* linf_bus_W = (const float*)d_in[28];
    const float* linf_bus_b = (const float*)d_in[29];
    const float* lin0_gen_W = (const float*)d_in[30];
    const float* lin0_gen_b = (const float*)d_in[31];
    const float* linf_gen_W = (const float*)d_in[32];
    const float* linf_gen_b = (const float*)d_in[33];

    // Workspace layout (~75 MB).
    char* ws = (char*)d_ws;
    size_t off = 0;
    auto alloc = [&](size_t bytes) {
        char* p = ws + off;
        off += (bytes + 255) & ~(size_t)255;
        return p;
    };
    unsigned* rs_bb = (unsigned*)alloc((size_t)N_BUS * 4);
    unsigned* rs_gb = (unsigned*)alloc((size_t)N_BUS * 4);
    unsigned* rs_bg = (unsigned*)alloc((size_t)N_GEN * 4);
    unsigned* cur_bb = (unsigned*)alloc(NBINS * 4);
    unsigned* cur_gb = (unsigned*)alloc(NBINS * 4);
    unsigned* cur_bg = (unsigned*)alloc(NBINS * 4);
    unsigned* e_bb = (unsigned*)alloc((size_t)E_BB * 4);
    unsigned* e_gb = (unsigned*)alloc((size_t)E_GB * 4);
    unsigned* e_bg = (unsigned*)alloc((size_t)E_BG * 4);
    unsigned short* y_bb = (unsigned short*)alloc((size_t)N_BUS * H * 2);  // bf16
    unsigned short* y_bg = (unsigned short*)alloc((size_t)N_BUS * H * 2);  // bf16
    unsigned short* y_gb = (unsigned short*)alloc((size_t)N_GEN * H * 2);  // bf16
    float* h_bus = (float*)alloc((size_t)N_BUS * H * 4);
    float* h_gen = (float*)alloc((size_t)N_GEN * H * 4);
    unsigned short* Wf1b = (unsigned short*)alloc(2 * 6 * 64 * 8 * 2);
    float* B1b = (float*)alloc(96 * 4);
    unsigned short* Wf1g = (unsigned short*)alloc(2 * 4 * 64 * 8 * 2);
    float* B1g = (float*)alloc(64 * 4);
    unsigned short* Wf2b = (unsigned short*)alloc(6 * 64 * 8 * 2);
    float* B2b = (float*)alloc(96 * 4);
    unsigned short* Wf2g = (unsigned short*)alloc(4 * 64 * 8 * 2);
    float* B2g = (float*)alloc(64 * 4);
    float* WeB = (float*)alloc(128 * 4);
    float* beB = (float*)alloc(4 * 4);
    float* WeG = (float*)alloc(64 * 4);
    float* beG = (float*)alloc(2 * 4);

    // Pair buffers alias y_* (CSR build completes before transforms write y).
    unsigned* p_bb = (unsigned*)y_bb;  // 6.4 MB <= 12.8 MB
    unsigned* p_gb = (unsigned*)y_bg;  // 1.6 MB <= 12.8 MB
    unsigned* p_bg = (unsigned*)y_gb;  // 1.6 MB <= 3.2 MB

    // Weights -> MFMA fragment order + fused head matrices.
    prep_kernel<<<32, 256, 0, stream>>>(
        l1_bb_Wl, l1_bb_bl, l1_bb_Wr, l1_gb_Wl, l1_gb_bl, l1_gb_Wr,
        l1_bg_Wl, l1_bg_bl, l1_bg_Wr, l2_bb_Wl, l2_bb_bl, l2_bb_Wr,
        l2_gb_Wl, l2_gb_bl, l2_gb_Wr, l2_bg_Wl, l2_bg_bl, l2_bg_Wr,
        lin0_bus_W, lin0_bus_b, linf_bus_W, linf_bus_b,
        lin0_gen_W, lin0_gen_b, linf_gen_W, linf_gen_b,
        Wf1b, B1b, Wf1g, B1g, Wf2b, B2b, Wf2g, B2g, WeB, beB, WeG, beG);

    // cursors are contiguous: one memset.
    hipMemsetAsync(cur_bb, 0, 3 * NBINS * 4, stream);

    // ---- CSR build, merged (4 dispatches) ----
    hist_all_kernel<<<448, 256, 0, stream>>>(dst_bb, dst_gb, dst_bg, cur_bb, cur_gb, cur_bg);
    scan_all_kernel<<<3, 256, 0, stream>>>(cur_bb, cur_gb, cur_bg);
    part_all_kernel<<<NB_PART_BB + NB_PART_GB + NB_PART_BG, 256, 0, stream>>>(
        src_bb, dst_bb, cur_bb, p_bb, src_gb, dst_gb, cur_gb, p_gb, src_bg, dst_bg, cur_bg, p_bg);
    fine_all_kernel<<<2 * NB_CSR_BUS + NB_CSR_GEN, 256, 0, stream>>>(
        cur_bb, p_bb, rs_bb, e_bb, cur_gb, p_gb, rs_gb, e_gb, cur_bg, p_bg, rs_bg, e_bg);

    // ---- Layer 1 ----
    tf_all_kernel<64, false><<<NB_TF_BUS + NB_TF_GEN, 256, 0, stream>>>(
        x_bus, Wf1b, B1b, y_bb, y_bg, h_bus, x_gen, Wf1g, B1g, y_gb, h_gen);
    pull_all_kernel<false><<<NB_PL_BUS + NB_PL_GEN, 256, 0, stream>>>(
        rs_bb, e_bb, y_bb, rs_gb, e_gb, y_gb, h_bus, WeB, beB,
        rs_bg, e_bg, y_bg, h_gen, WeG, beG, nullptr);

    // ---- Layer 2 (relu on staging; root written in-place over h_*) ----
    tf_all_kernel<32, true><<<NB_TF_BUS + NB_TF_GEN, 256, 0, stream>>>(
        h_bus, Wf2b, B2b, y_bb, y_bg, h_bus, h_gen, Wf2g, B2g, y_gb, h_gen);
    // Pull 2 with fused head -> writes d_out directly.
    pull_all_kernel<true><<<NB_PL_BUS + NB_PL_GEN, 256, 0, stream>>>(
        rs_bb, e_bb, y_bb, rs_gb, e_gb, y_gb, h_bus, WeB, beB,
        rs_bg, e_bg, y_bg, h_gen, WeG, beG, (float*)d_out);
}